// Round 1
// baseline (361.429 us; speedup 1.0000x reference)
//
#include <hip/hip_runtime.h>

#define N_NODES 50000
#define N_EDGES 600000
#define SCAN_BLOCKS ((N_NODES + 1023) / 1024)

// ---------------- CSR build ----------------

__global__ void count_deg(const int* __restrict__ ei, int* __restrict__ deg) {
    int e = blockIdx.x * 256 + threadIdx.x;
    if (e < N_EDGES) atomicAdd(&deg[ei[N_EDGES + e]], 1);
}

__global__ void scan_blocks_k(const int* __restrict__ deg, int* __restrict__ rs,
                              int* __restrict__ partials) {
    __shared__ int sm[1024];
    int i = blockIdx.x * 1024 + threadIdx.x;
    int v = (i < N_NODES) ? deg[i] : 0;
    sm[threadIdx.x] = v;
    __syncthreads();
    // Hillis-Steele inclusive scan
    for (int off = 1; off < 1024; off <<= 1) {
        int t = (threadIdx.x >= off) ? sm[threadIdx.x - off] : 0;
        __syncthreads();
        sm[threadIdx.x] += t;
        __syncthreads();
    }
    if (i < N_NODES) rs[i] = sm[threadIdx.x] - v;  // exclusive
    if (threadIdx.x == 1023) partials[blockIdx.x] = sm[1023];
}

__global__ void scan_partials_k(int* __restrict__ partials, int nb) {
    int tid = threadIdx.x;  // single wave of 64, nb <= 64
    int v = (tid < nb) ? partials[tid] : 0;
    int orig = v;
    for (int off = 1; off < 64; off <<= 1) {
        int t = __shfl_up(v, off, 64);
        if (tid >= off) v += t;
    }
    if (tid < nb) partials[tid] = v - orig;  // exclusive offsets
}

__global__ void finalize_csr(int* __restrict__ rs, const int* __restrict__ partials,
                             int* __restrict__ cursor, float* __restrict__ dinv,
                             const int* __restrict__ deg) {
    int i = blockIdx.x * 256 + threadIdx.x;
    if (i < N_NODES) {
        int r = rs[i] + partials[i >> 10];
        rs[i] = r;
        cursor[i] = r;
        dinv[i] = rsqrtf((float)(deg[i] + 1));  // +1 self-loop; deg>=1 always
    }
    if (i == 0) rs[N_NODES] = N_EDGES;
}

__global__ void fill_csr(const int* __restrict__ ei, int* __restrict__ cursor,
                         int* __restrict__ col) {
    int e = blockIdx.x * 256 + threadIdx.x;
    if (e < N_EDGES) {
        int s = ei[e];
        int d = ei[N_EDGES + e];
        int pos = atomicAdd(&cursor[d], 1);
        col[pos] = s;
    }
}

// ---------------- GEMM: out[m, :] = (A[m, :] @ W) * dinv[m] ----------------
// BM=BN=64, BK=16, 256 threads, 4x4 micro-tile per thread.

template <int K, int NOUT>
__global__ __launch_bounds__(256) void gemm_scale(const float* __restrict__ A,
                                                  const float* __restrict__ W,
                                                  const float* __restrict__ dinv,
                                                  float* __restrict__ out) {
    __shared__ float As[16][68];  // stored transposed [k][m]; 68 keeps 16B alignment
    __shared__ float Bs[16][68];
    const int tid = threadIdx.x;
    const int m0 = blockIdx.x * 64;
    const int n0 = blockIdx.y * 64;
    const int tx = tid & 15, ty = tid >> 4;
    const int arow = tid >> 2, acol = (tid & 3) * 4;
    const int brow = tid >> 4, bcol = (tid & 15) * 4;
    float acc[4][4] = {};

    for (int kt = 0; kt < K; kt += 16) {
        float4 av = make_float4(0.f, 0.f, 0.f, 0.f);
        if (m0 + arow < N_NODES)
            av = *(const float4*)&A[(size_t)(m0 + arow) * K + kt + acol];
        As[acol + 0][arow] = av.x;
        As[acol + 1][arow] = av.y;
        As[acol + 2][arow] = av.z;
        As[acol + 3][arow] = av.w;
        *(float4*)&Bs[brow][bcol] =
            *(const float4*)&W[(size_t)(kt + brow) * NOUT + n0 + bcol];
        __syncthreads();
#pragma unroll
        for (int k = 0; k < 16; ++k) {
            float4 a = *(const float4*)&As[k][ty * 4];
            float4 b = *(const float4*)&Bs[k][tx * 4];
            float aa[4] = {a.x, a.y, a.z, a.w};
            float bb[4] = {b.x, b.y, b.z, b.w};
#pragma unroll
            for (int i = 0; i < 4; ++i)
#pragma unroll
                for (int j = 0; j < 4; ++j) acc[i][j] = fmaf(aa[i], bb[j], acc[i][j]);
        }
        __syncthreads();
    }
#pragma unroll
    for (int i = 0; i < 4; ++i) {
        int row = m0 + ty * 4 + i;
        if (row < N_NODES) {
            float dv = dinv[row];
            float4 o = make_float4(acc[i][0] * dv, acc[i][1] * dv, acc[i][2] * dv,
                                   acc[i][3] * dv);
            *(float4*)&out[(size_t)row * NOUT + n0 + tx * 4] = o;
        }
    }
}

// ---------------- Aggregation (pull over CSR) + bias + ReLU ----------------
// out[i,f] = relu(dinv[i] * (hs[i,f] + sum_{e in row i} hs[col[e], f]) + bias[f])

template <int F>
__global__ __launch_bounds__(256) void agg_relu(const float* __restrict__ hs,
                                                const int* __restrict__ rs,
                                                const int* __restrict__ col,
                                                const float* __restrict__ dinv,
                                                const float* __restrict__ bias,
                                                float* __restrict__ out) {
    const int per = 256 / F;
    int node = blockIdx.x * per + threadIdx.x / F;
    int f = threadIdx.x % F;
    if (node >= N_NODES) return;
    float acc = hs[(size_t)node * F + f];
    int e0 = rs[node], e1 = rs[node + 1];
    for (int e = e0; e < e1; ++e) {
        int s = col[e];
        acc += hs[(size_t)s * F + f];
    }
    out[(size_t)node * F + f] = fmaxf(fmaf(dinv[node], acc, bias[f]), 0.f);
}

// ---------------- Layer-2 aggregation fused with ReLU and the D->1 head ----
// out[i] = b3 + sum_f relu(dinv[i]*(agg hs2) + b2[f]) * W3[f]

__global__ __launch_bounds__(256) void agg_final(const float* __restrict__ hs,
                                                 const int* __restrict__ rs,
                                                 const int* __restrict__ col,
                                                 const float* __restrict__ dinv,
                                                 const float* __restrict__ b2,
                                                 const float* __restrict__ W3,
                                                 const float* __restrict__ b3,
                                                 float* __restrict__ out) {
    int node = blockIdx.x * 4 + (threadIdx.x >> 6);  // one wave per node
    int f = threadIdx.x & 63;
    if (node >= N_NODES) return;
    float acc = hs[node * 64 + f];
    int e0 = rs[node], e1 = rs[node + 1];
    for (int e = e0; e < e1; ++e) acc += hs[col[e] * 64 + f];
    float v = fmaxf(fmaf(dinv[node], acc, b2[f]), 0.f) * W3[f];
#pragma unroll
    for (int off = 32; off > 0; off >>= 1) v += __shfl_down(v, off, 64);
    if (f == 0) out[node] = v + b3[0];
}

// ---------------- launch ----------------

extern "C" void kernel_launch(void* const* d_in, const int* in_sizes, int n_in,
                              void* d_out, int out_size, void* d_ws, size_t ws_size,
                              hipStream_t stream) {
    const float* x  = (const float*)d_in[0];
    const int*   ei = (const int*)d_in[1];   // [2, E]: row 0 = src, row 1 = dst
    const float* W1 = (const float*)d_in[2];
    const float* b1 = (const float*)d_in[3];
    const float* W2 = (const float*)d_in[4];
    const float* b2 = (const float*)d_in[5];
    const float* W3 = (const float*)d_in[6];
    const float* b3 = (const float*)d_in[7];
    float* out = (float*)d_out;

    char* ws = (char*)d_ws;
    size_t off = 0;
    auto alloc = [&](size_t bytes) -> void* {
        void* p = ws + off;
        off = (off + bytes + 255) & ~(size_t)255;
        return p;
    };
    int*   deg      = (int*)alloc(N_NODES * sizeof(int));
    int*   rs       = (int*)alloc((N_NODES + 1) * sizeof(int));
    int*   cursor   = (int*)alloc(N_NODES * sizeof(int));
    int*   partials = (int*)alloc(64 * sizeof(int));
    int*   col      = (int*)alloc(N_EDGES * sizeof(int));
    float* dinv     = (float*)alloc(N_NODES * sizeof(float));
    float* hs1      = (float*)alloc((size_t)N_NODES * 128 * sizeof(float));
    float* t1       = (float*)alloc((size_t)N_NODES * 128 * sizeof(float));
    float* hs2      = (float*)alloc((size_t)N_NODES * 64 * sizeof(float));

    hipMemsetAsync(deg, 0, N_NODES * sizeof(int), stream);
    count_deg<<<(N_EDGES + 255) / 256, 256, 0, stream>>>(ei, deg);
    scan_blocks_k<<<SCAN_BLOCKS, 1024, 0, stream>>>(deg, rs, partials);
    scan_partials_k<<<1, 64, 0, stream>>>(partials, SCAN_BLOCKS);
    finalize_csr<<<(N_NODES + 255) / 256, 256, 0, stream>>>(rs, partials, cursor, dinv, deg);
    fill_csr<<<(N_EDGES + 255) / 256, 256, 0, stream>>>(ei, cursor, col);

    gemm_scale<128, 128><<<dim3((N_NODES + 63) / 64, 2), 256, 0, stream>>>(x, W1, dinv, hs1);
    agg_relu<128><<<(N_NODES + 1) / 2, 256, 0, stream>>>(hs1, rs, col, dinv, b1, t1);
    gemm_scale<128, 64><<<dim3((N_NODES + 63) / 64, 1), 256, 0, stream>>>(t1, W2, dinv, hs2);
    agg_final<<<(N_NODES + 3) / 4, 256, 0, stream>>>(hs2, rs, col, dinv, b2, W3, b3, out);
}

// Round 2
// 254.327 us; speedup vs baseline: 1.4211x; 1.4211x over previous
//
#include <hip/hip_runtime.h>

#define N_NODES 50000
#define N_EDGES 600000
#define SCAN_BLOCKS ((N_NODES + 1023) / 1024)

// ---------------- CSR build ----------------

__global__ void count_deg(const int* __restrict__ ei, int* __restrict__ deg) {
    int e = blockIdx.x * 256 + threadIdx.x;
    if (e < N_EDGES) atomicAdd(&deg[ei[N_EDGES + e]], 1);
}

__global__ void scan_blocks_k(const int* __restrict__ deg, int* __restrict__ rs,
                              int* __restrict__ partials) {
    __shared__ int sm[1024];
    int i = blockIdx.x * 1024 + threadIdx.x;
    int v = (i < N_NODES) ? deg[i] : 0;
    sm[threadIdx.x] = v;
    __syncthreads();
    for (int off = 1; off < 1024; off <<= 1) {
        int t = (threadIdx.x >= off) ? sm[threadIdx.x - off] : 0;
        __syncthreads();
        sm[threadIdx.x] += t;
        __syncthreads();
    }
    if (i < N_NODES) rs[i] = sm[threadIdx.x] - v;  // exclusive
    if (threadIdx.x == 1023) partials[blockIdx.x] = sm[1023];
}

__global__ void scan_partials_k(int* __restrict__ partials, int nb) {
    int tid = threadIdx.x;  // single wave of 64, nb <= 64
    int v = (tid < nb) ? partials[tid] : 0;
    int orig = v;
    for (int off = 1; off < 64; off <<= 1) {
        int t = __shfl_up(v, off, 64);
        if (tid >= off) v += t;
    }
    if (tid < nb) partials[tid] = v - orig;  // exclusive offsets
}

__global__ void finalize_csr(int* __restrict__ rs, const int* __restrict__ partials,
                             int* __restrict__ cursor, float* __restrict__ dinv,
                             const int* __restrict__ deg) {
    int i = blockIdx.x * 256 + threadIdx.x;
    if (i < N_NODES) {
        int r = rs[i] + partials[i >> 10];
        rs[i] = r;
        cursor[i] = r;
        dinv[i] = rsqrtf((float)(deg[i] + 1));  // +1 self-loop
    }
    if (i == 0) rs[N_NODES] = N_EDGES;
}

__global__ void fill_csr(const int* __restrict__ ei, int* __restrict__ cursor,
                         int* __restrict__ col) {
    int e = blockIdx.x * 256 + threadIdx.x;
    if (e < N_EDGES) {
        int s = ei[e];
        int d = ei[N_EDGES + e];
        int pos = atomicAdd(&cursor[d], 1);
        col[pos] = s;
    }
}

// ---------------- GEMM: out[m, :] = (A[m, :] @ W) * dinv[m] ----------------

template <int K, int NOUT>
__global__ __launch_bounds__(256) void gemm_scale(const float* __restrict__ A,
                                                  const float* __restrict__ W,
                                                  const float* __restrict__ dinv,
                                                  float* __restrict__ out) {
    __shared__ float As[16][68];
    __shared__ float Bs[16][68];
    const int tid = threadIdx.x;
    const int m0 = blockIdx.x * 64;
    const int n0 = blockIdx.y * 64;
    const int tx = tid & 15, ty = tid >> 4;
    const int arow = tid >> 2, acol = (tid & 3) * 4;
    const int brow = tid >> 4, bcol = (tid & 15) * 4;
    float acc[4][4] = {};

    for (int kt = 0; kt < K; kt += 16) {
        float4 av = make_float4(0.f, 0.f, 0.f, 0.f);
        if (m0 + arow < N_NODES)
            av = *(const float4*)&A[(size_t)(m0 + arow) * K + kt + acol];
        As[acol + 0][arow] = av.x;
        As[acol + 1][arow] = av.y;
        As[acol + 2][arow] = av.z;
        As[acol + 3][arow] = av.w;
        *(float4*)&Bs[brow][bcol] =
            *(const float4*)&W[(size_t)(kt + brow) * NOUT + n0 + bcol];
        __syncthreads();
#pragma unroll
        for (int k = 0; k < 16; ++k) {
            float4 a = *(const float4*)&As[k][ty * 4];
            float4 b = *(const float4*)&Bs[k][tx * 4];
            float aa[4] = {a.x, a.y, a.z, a.w};
            float bb[4] = {b.x, b.y, b.z, b.w};
#pragma unroll
            for (int i = 0; i < 4; ++i)
#pragma unroll
                for (int j = 0; j < 4; ++j) acc[i][j] = fmaf(aa[i], bb[j], acc[i][j]);
        }
        __syncthreads();
    }
#pragma unroll
    for (int i = 0; i < 4; ++i) {
        int row = m0 + ty * 4 + i;
        if (row < N_NODES) {
            float dv = dinv[row];
            float4 o = make_float4(acc[i][0] * dv, acc[i][1] * dv, acc[i][2] * dv,
                                   acc[i][3] * dv);
            *(float4*)&out[(size_t)row * NOUT + n0 + tx * 4] = o;
        }
    }
}

// ---------------- Layer-1 aggregation: float4 lanes + unrolled pipeline ----
// 32 lanes per node, each lane owns 4 features. 8 nodes per 256-thread block.

__global__ __launch_bounds__(256) void agg_relu128(const float* __restrict__ hs,
                                                   const int* __restrict__ rs,
                                                   const int* __restrict__ col,
                                                   const float* __restrict__ dinv,
                                                   const float* __restrict__ bias,
                                                   float* __restrict__ out) {
    int node = blockIdx.x * 8 + (threadIdx.x >> 5);
    int lane = threadIdx.x & 31;
    if (node >= N_NODES) return;
    const int fo = lane * 4;
    float4 acc = *(const float4*)&hs[(size_t)node * 128 + fo];
    int e = rs[node], e1 = rs[node + 1];
    for (; e + 4 <= e1; e += 4) {
        int s0 = col[e], s1 = col[e + 1], s2 = col[e + 2], s3 = col[e + 3];
        float4 v0 = *(const float4*)&hs[(size_t)s0 * 128 + fo];
        float4 v1 = *(const float4*)&hs[(size_t)s1 * 128 + fo];
        float4 v2 = *(const float4*)&hs[(size_t)s2 * 128 + fo];
        float4 v3 = *(const float4*)&hs[(size_t)s3 * 128 + fo];
        acc.x += (v0.x + v1.x) + (v2.x + v3.x);
        acc.y += (v0.y + v1.y) + (v2.y + v3.y);
        acc.z += (v0.z + v1.z) + (v2.z + v3.z);
        acc.w += (v0.w + v1.w) + (v2.w + v3.w);
    }
    for (; e < e1; ++e) {
        float4 v = *(const float4*)&hs[(size_t)col[e] * 128 + fo];
        acc.x += v.x; acc.y += v.y; acc.z += v.z; acc.w += v.w;
    }
    float dv = dinv[node];
    float4 b = *(const float4*)&bias[fo];
    float4 o;
    o.x = fmaxf(fmaf(dv, acc.x, b.x), 0.f);
    o.y = fmaxf(fmaf(dv, acc.y, b.y), 0.f);
    o.z = fmaxf(fmaf(dv, acc.z, b.z), 0.f);
    o.w = fmaxf(fmaf(dv, acc.w, b.w), 0.f);
    *(float4*)&out[(size_t)node * 128 + fo] = o;
}

// ---------------- Layer-2 aggregation + ReLU + D->1 head -------------------
// 16 lanes per node (float4 x 16 = 64 features), 16 nodes per 256-thread block.

__global__ __launch_bounds__(256) void agg_final(const float* __restrict__ hs,
                                                 const int* __restrict__ rs,
                                                 const int* __restrict__ col,
                                                 const float* __restrict__ dinv,
                                                 const float* __restrict__ b2,
                                                 const float* __restrict__ W3,
                                                 const float* __restrict__ b3,
                                                 float* __restrict__ out) {
    int node = blockIdx.x * 16 + (threadIdx.x >> 4);
    int lane = threadIdx.x & 15;
    if (node >= N_NODES) return;
    const int fo = lane * 4;
    float4 acc = *(const float4*)&hs[(size_t)node * 64 + fo];
    int e = rs[node], e1 = rs[node + 1];
    for (; e + 4 <= e1; e += 4) {
        int s0 = col[e], s1 = col[e + 1], s2 = col[e + 2], s3 = col[e + 3];
        float4 v0 = *(const float4*)&hs[(size_t)s0 * 64 + fo];
        float4 v1 = *(const float4*)&hs[(size_t)s1 * 64 + fo];
        float4 v2 = *(const float4*)&hs[(size_t)s2 * 64 + fo];
        float4 v3 = *(const float4*)&hs[(size_t)s3 * 64 + fo];
        acc.x += (v0.x + v1.x) + (v2.x + v3.x);
        acc.y += (v0.y + v1.y) + (v2.y + v3.y);
        acc.z += (v0.z + v1.z) + (v2.z + v3.z);
        acc.w += (v0.w + v1.w) + (v2.w + v3.w);
    }
    for (; e < e1; ++e) {
        float4 v = *(const float4*)&hs[(size_t)col[e] * 64 + fo];
        acc.x += v.x; acc.y += v.y; acc.z += v.z; acc.w += v.w;
    }
    float dv = dinv[node];
    float4 b = *(const float4*)&b2[fo];
    float4 w = *(const float4*)&W3[fo];
    float v = fmaxf(fmaf(dv, acc.x, b.x), 0.f) * w.x +
              fmaxf(fmaf(dv, acc.y, b.y), 0.f) * w.y +
              fmaxf(fmaf(dv, acc.z, b.z), 0.f) * w.z +
              fmaxf(fmaf(dv, acc.w, b.w), 0.f) * w.w;
    // reduce across the 16-lane group
#pragma unroll
    for (int m = 8; m > 0; m >>= 1) v += __shfl_xor(v, m, 64);
    if (lane == 0) out[node] = v + b3[0];
}

// ---------------- launch ----------------

extern "C" void kernel_launch(void* const* d_in, const int* in_sizes, int n_in,
                              void* d_out, int out_size, void* d_ws, size_t ws_size,
                              hipStream_t stream) {
    const float* x  = (const float*)d_in[0];
    const int*   ei = (const int*)d_in[1];
    const float* W1 = (const float*)d_in[2];
    const float* b1 = (const float*)d_in[3];
    const float* W2 = (const float*)d_in[4];
    const float* b2 = (const float*)d_in[5];
    const float* W3 = (const float*)d_in[6];
    const float* b3 = (const float*)d_in[7];
    float* out = (float*)d_out;

    char* ws = (char*)d_ws;
    size_t off = 0;
    auto alloc = [&](size_t bytes) -> void* {
        void* p = ws + off;
        off = (off + bytes + 255) & ~(size_t)255;
        return p;
    };
    int*   deg      = (int*)alloc(N_NODES * sizeof(int));
    int*   rs       = (int*)alloc((N_NODES + 1) * sizeof(int));
    int*   cursor   = (int*)alloc(N_NODES * sizeof(int));
    int*   partials = (int*)alloc(64 * sizeof(int));
    int*   col      = (int*)alloc(N_EDGES * sizeof(int));
    float* dinv     = (float*)alloc(N_NODES * sizeof(float));
    float* hs1      = (float*)alloc((size_t)N_NODES * 128 * sizeof(float));
    float* t1       = (float*)alloc((size_t)N_NODES * 128 * sizeof(float));
    float* hs2      = (float*)alloc((size_t)N_NODES * 64 * sizeof(float));

    hipMemsetAsync(deg, 0, N_NODES * sizeof(int), stream);
    count_deg<<<(N_EDGES + 255) / 256, 256, 0, stream>>>(ei, deg);
    scan_blocks_k<<<SCAN_BLOCKS, 1024, 0, stream>>>(deg, rs, partials);
    scan_partials_k<<<1, 64, 0, stream>>>(partials, SCAN_BLOCKS);
    finalize_csr<<<(N_NODES + 255) / 256, 256, 0, stream>>>(rs, partials, cursor, dinv, deg);
    fill_csr<<<(N_EDGES + 255) / 256, 256, 0, stream>>>(ei, cursor, col);

    gemm_scale<128, 128><<<dim3((N_NODES + 63) / 64, 2), 256, 0, stream>>>(x, W1, dinv, hs1);
    agg_relu128<<<(N_NODES + 7) / 8, 256, 0, stream>>>(hs1, rs, col, dinv, b1, t1);
    gemm_scale<128, 64><<<dim3((N_NODES + 63) / 64, 1), 256, 0, stream>>>(t1, W2, dinv, hs2);
    agg_final<<<(N_NODES + 15) / 16, 256, 0, stream>>>(hs2, rs, col, dinv, b2, W3, b3, out);
}

// Round 3
// 235.894 us; speedup vs baseline: 1.5322x; 1.0781x over previous
//
#include <hip/hip_runtime.h>

#define N_NODES 50000
#define N_EDGES 600000
#define SCAN_BLOCKS ((N_NODES + 1023) / 1024)

typedef unsigned int u32;
typedef unsigned short u16;

__device__ __forceinline__ u16 f2bf(float f) {
    u32 u = __float_as_uint(f);
    u32 r = (u + 0x7fffu + ((u >> 16) & 1u)) >> 16;  // RNE
    return (u16)r;
}
__device__ __forceinline__ float bf_lo(u32 u) { return __uint_as_float(u << 16); }
__device__ __forceinline__ float bf_hi(u32 u) { return __uint_as_float(u & 0xffff0000u); }

// ---------------- CSR build ----------------

__global__ void count_deg(const int* __restrict__ ei, int* __restrict__ deg) {
    int e = blockIdx.x * 256 + threadIdx.x;
    if (e < N_EDGES) atomicAdd(&deg[ei[N_EDGES + e]], 1);
}

__global__ __launch_bounds__(1024) void scan_blocks_k(const int* __restrict__ deg,
                                                      int* __restrict__ rs,
                                                      int* __restrict__ partials) {
    __shared__ int wsum[16];
    int i = blockIdx.x * 1024 + threadIdx.x;
    int v = (i < N_NODES) ? deg[i] : 0;
    int lane = threadIdx.x & 63, w = threadIdx.x >> 6;
    int s = v;
#pragma unroll
    for (int off = 1; off < 64; off <<= 1) {
        int t = __shfl_up(s, off, 64);
        if (lane >= off) s += t;
    }
    if (lane == 63) wsum[w] = s;
    __syncthreads();
    if (w == 0) {
        int ws = (lane < 16) ? wsum[lane] : 0;
#pragma unroll
        for (int off = 1; off < 16; off <<= 1) {
            int t = __shfl_up(ws, off, 64);
            if (lane >= off) ws += t;
        }
        if (lane < 16) wsum[lane] = ws;
    }
    __syncthreads();
    int incl = s + ((w > 0) ? wsum[w - 1] : 0);
    if (i < N_NODES) rs[i] = incl - v;  // exclusive
    if (threadIdx.x == 1023) partials[blockIdx.x] = incl;
}

__global__ void scan_partials_k(int* __restrict__ partials, int nb) {
    int tid = threadIdx.x;  // single wave, nb <= 64
    int v = (tid < nb) ? partials[tid] : 0;
    int orig = v;
    for (int off = 1; off < 64; off <<= 1) {
        int t = __shfl_up(v, off, 64);
        if (tid >= off) v += t;
    }
    if (tid < nb) partials[tid] = v - orig;
}

__global__ void finalize_csr(int* __restrict__ rs, const int* __restrict__ partials,
                             int* __restrict__ cursor, float* __restrict__ dinv,
                             const int* __restrict__ deg) {
    int i = blockIdx.x * 256 + threadIdx.x;
    if (i < N_NODES) {
        int r = rs[i] + partials[i >> 10];
        rs[i] = r;
        cursor[i] = r;
        dinv[i] = rsqrtf((float)(deg[i] + 1));
    }
    if (i == 0) rs[N_NODES] = N_EDGES;
}

__global__ void fill_csr(const int* __restrict__ ei, int* __restrict__ cursor,
                         int* __restrict__ col) {
    int e = blockIdx.x * 256 + threadIdx.x;
    if (e < N_EDGES) {
        int s = ei[e];
        int d = ei[N_EDGES + e];
        int pos = atomicAdd(&cursor[d], 1);
        col[pos] = s;
    }
}

// ---------------- GEMM: out[m, :] = bf16((A[m, :] @ W) * dinv[m]) ----------

template <int K, int NOUT>
__global__ __launch_bounds__(256) void gemm_scale_bf(const float* __restrict__ A,
                                                     const float* __restrict__ W,
                                                     const float* __restrict__ dinv,
                                                     u16* __restrict__ out) {
    __shared__ float As[16][68];
    __shared__ float Bs[16][68];
    const int tid = threadIdx.x;
    const int m0 = blockIdx.x * 64;
    const int n0 = blockIdx.y * 64;
    const int tx = tid & 15, ty = tid >> 4;
    const int arow = tid >> 2, acol = (tid & 3) * 4;
    const int brow = tid >> 4, bcol = (tid & 15) * 4;
    float acc[4][4] = {};

    for (int kt = 0; kt < K; kt += 16) {
        float4 av = make_float4(0.f, 0.f, 0.f, 0.f);
        if (m0 + arow < N_NODES)
            av = *(const float4*)&A[(size_t)(m0 + arow) * K + kt + acol];
        As[acol + 0][arow] = av.x;
        As[acol + 1][arow] = av.y;
        As[acol + 2][arow] = av.z;
        As[acol + 3][arow] = av.w;
        *(float4*)&Bs[brow][bcol] =
            *(const float4*)&W[(size_t)(kt + brow) * NOUT + n0 + bcol];
        __syncthreads();
#pragma unroll
        for (int k = 0; k < 16; ++k) {
            float4 a = *(const float4*)&As[k][ty * 4];
            float4 b = *(const float4*)&Bs[k][tx * 4];
            float aa[4] = {a.x, a.y, a.z, a.w};
            float bb[4] = {b.x, b.y, b.z, b.w};
#pragma unroll
            for (int i = 0; i < 4; ++i)
#pragma unroll
                for (int j = 0; j < 4; ++j) acc[i][j] = fmaf(aa[i], bb[j], acc[i][j]);
        }
        __syncthreads();
    }
#pragma unroll
    for (int i = 0; i < 4; ++i) {
        int row = m0 + ty * 4 + i;
        if (row < N_NODES) {
            float dv = dinv[row];
            u32 lo = (u32)f2bf(acc[i][0] * dv) | ((u32)f2bf(acc[i][1] * dv) << 16);
            u32 hi = (u32)f2bf(acc[i][2] * dv) | ((u32)f2bf(acc[i][3] * dv) << 16);
            uint2 pk = make_uint2(lo, hi);
            *(uint2*)&out[(size_t)row * NOUT + n0 + tx * 4] = pk;
        }
    }
}

// ---------------- Layer-1 aggregation (bf16 gather) + bias + ReLU ----------
// 16 lanes per node, each lane owns 8 features (one uint4 = 16B of the 256B row).

__global__ __launch_bounds__(256) void agg_relu128_bf(const u16* __restrict__ hs,
                                                      const int* __restrict__ rs,
                                                      const int* __restrict__ col,
                                                      const float* __restrict__ dinv,
                                                      const float* __restrict__ bias,
                                                      float* __restrict__ out) {
    int node = blockIdx.x * 16 + (threadIdx.x >> 4);
    int lane = threadIdx.x & 15;
    if (node >= N_NODES) return;
    const uint4* rows = (const uint4*)hs;  // 16 uint4 per row
    float acc[8] = {};
    auto accum = [&](uint4 v) {
        acc[0] += bf_lo(v.x); acc[1] += bf_hi(v.x);
        acc[2] += bf_lo(v.y); acc[3] += bf_hi(v.y);
        acc[4] += bf_lo(v.z); acc[5] += bf_hi(v.z);
        acc[6] += bf_lo(v.w); acc[7] += bf_hi(v.w);
    };
    accum(rows[(size_t)node * 16 + lane]);  // self-loop
    int e = rs[node], e1 = rs[node + 1];
    for (; e + 4 <= e1; e += 4) {
        int s0 = col[e], s1 = col[e + 1], s2 = col[e + 2], s3 = col[e + 3];
        uint4 v0 = rows[(size_t)s0 * 16 + lane];
        uint4 v1 = rows[(size_t)s1 * 16 + lane];
        uint4 v2 = rows[(size_t)s2 * 16 + lane];
        uint4 v3 = rows[(size_t)s3 * 16 + lane];
        accum(v0); accum(v1); accum(v2); accum(v3);
    }
    for (; e < e1; ++e) accum(rows[(size_t)col[e] * 16 + lane]);
    float dv = dinv[node];
    int fo = lane * 8;
    float4 o0, o1;
    o0.x = fmaxf(fmaf(dv, acc[0], bias[fo + 0]), 0.f);
    o0.y = fmaxf(fmaf(dv, acc[1], bias[fo + 1]), 0.f);
    o0.z = fmaxf(fmaf(dv, acc[2], bias[fo + 2]), 0.f);
    o0.w = fmaxf(fmaf(dv, acc[3], bias[fo + 3]), 0.f);
    o1.x = fmaxf(fmaf(dv, acc[4], bias[fo + 4]), 0.f);
    o1.y = fmaxf(fmaf(dv, acc[5], bias[fo + 5]), 0.f);
    o1.z = fmaxf(fmaf(dv, acc[6], bias[fo + 6]), 0.f);
    o1.w = fmaxf(fmaf(dv, acc[7], bias[fo + 7]), 0.f);
    *(float4*)&out[(size_t)node * 128 + fo] = o0;
    *(float4*)&out[(size_t)node * 128 + fo + 4] = o1;
}

// ---------------- Layer-2 aggregation (bf16 gather) + ReLU + D->1 head -----
// 8 lanes per node, each lane owns 8 features (one uint4 of the 128B row).

__global__ __launch_bounds__(256) void agg_final_bf(const u16* __restrict__ hs,
                                                    const int* __restrict__ rs,
                                                    const int* __restrict__ col,
                                                    const float* __restrict__ dinv,
                                                    const float* __restrict__ b2,
                                                    const float* __restrict__ W3,
                                                    const float* __restrict__ b3,
                                                    float* __restrict__ out) {
    int node = blockIdx.x * 32 + (threadIdx.x >> 3);
    int lane = threadIdx.x & 7;
    if (node >= N_NODES) return;
    const uint4* rows = (const uint4*)hs;  // 8 uint4 per row
    float acc[8] = {};
    auto accum = [&](uint4 v) {
        acc[0] += bf_lo(v.x); acc[1] += bf_hi(v.x);
        acc[2] += bf_lo(v.y); acc[3] += bf_hi(v.y);
        acc[4] += bf_lo(v.z); acc[5] += bf_hi(v.z);
        acc[6] += bf_lo(v.w); acc[7] += bf_hi(v.w);
    };
    accum(rows[(size_t)node * 8 + lane]);  // self-loop
    int e = rs[node], e1 = rs[node + 1];
    for (; e + 4 <= e1; e += 4) {
        int s0 = col[e], s1 = col[e + 1], s2 = col[e + 2], s3 = col[e + 3];
        uint4 v0 = rows[(size_t)s0 * 8 + lane];
        uint4 v1 = rows[(size_t)s1 * 8 + lane];
        uint4 v2 = rows[(size_t)s2 * 8 + lane];
        uint4 v3 = rows[(size_t)s3 * 8 + lane];
        accum(v0); accum(v1); accum(v2); accum(v3);
    }
    for (; e < e1; ++e) accum(rows[(size_t)col[e] * 8 + lane]);
    float dv = dinv[node];
    int fo = lane * 8;
    float v = 0.f;
#pragma unroll
    for (int j = 0; j < 8; ++j)
        v += fmaxf(fmaf(dv, acc[j], b2[fo + j]), 0.f) * W3[fo + j];
#pragma unroll
    for (int m = 4; m > 0; m >>= 1) v += __shfl_xor(v, m, 64);
    if (lane == 0) out[node] = v + b3[0];
}

// ---------------- launch ----------------

extern "C" void kernel_launch(void* const* d_in, const int* in_sizes, int n_in,
                              void* d_out, int out_size, void* d_ws, size_t ws_size,
                              hipStream_t stream) {
    const float* x  = (const float*)d_in[0];
    const int*   ei = (const int*)d_in[1];
    const float* W1 = (const float*)d_in[2];
    const float* b1 = (const float*)d_in[3];
    const float* W2 = (const float*)d_in[4];
    const float* b2 = (const float*)d_in[5];
    const float* W3 = (const float*)d_in[6];
    const float* b3 = (const float*)d_in[7];
    float* out = (float*)d_out;

    char* ws = (char*)d_ws;
    size_t off = 0;
    auto alloc = [&](size_t bytes) -> void* {
        void* p = ws + off;
        off = (off + bytes + 255) & ~(size_t)255;
        return p;
    };
    int*   deg      = (int*)alloc(N_NODES * sizeof(int));
    int*   rs       = (int*)alloc((N_NODES + 1) * sizeof(int));
    int*   cursor   = (int*)alloc(N_NODES * sizeof(int));
    int*   partials = (int*)alloc(64 * sizeof(int));
    int*   col      = (int*)alloc(N_EDGES * sizeof(int));
    float* dinv     = (float*)alloc(N_NODES * sizeof(float));
    u16*   hs1      = (u16*)alloc((size_t)N_NODES * 128 * sizeof(u16));   // bf16
    float* t1       = (float*)alloc((size_t)N_NODES * 128 * sizeof(float));
    u16*   hs2      = (u16*)alloc((size_t)N_NODES * 64 * sizeof(u16));    // bf16

    hipMemsetAsync(deg, 0, N_NODES * sizeof(int), stream);
    count_deg<<<(N_EDGES + 255) / 256, 256, 0, stream>>>(ei, deg);
    scan_blocks_k<<<SCAN_BLOCKS, 1024, 0, stream>>>(deg, rs, partials);
    scan_partials_k<<<1, 64, 0, stream>>>(partials, SCAN_BLOCKS);
    finalize_csr<<<(N_NODES + 255) / 256, 256, 0, stream>>>(rs, partials, cursor, dinv, deg);
    fill_csr<<<(N_EDGES + 255) / 256, 256, 0, stream>>>(ei, cursor, col);

    gemm_scale_bf<128, 128><<<dim3((N_NODES + 63) / 64, 2), 256, 0, stream>>>(x, W1, dinv, hs1);
    agg_relu128_bf<<<(N_NODES + 15) / 16, 256, 0, stream>>>(hs1, rs, col, dinv, b1, t1);
    gemm_scale_bf<128, 64><<<dim3((N_NODES + 63) / 64, 1), 256, 0, stream>>>(t1, W2, dinv, hs2);
    agg_final_bf<<<(N_NODES + 31) / 32, 256, 0, stream>>>(hs2, rs, col, dinv, b2, W3, b3, out);
}

// Round 5
// 210.991 us; speedup vs baseline: 1.7130x; 1.1180x over previous
//
#include <hip/hip_runtime.h>

#define N_NODES 50000
#define N_EDGES 600000
#define SCAN_BLOCKS ((N_NODES + 1023) / 1024)

typedef unsigned int u32;
typedef unsigned short u16;
typedef __attribute__((ext_vector_type(8))) short short8;
typedef __attribute__((ext_vector_type(4))) float f32x4;

__device__ __forceinline__ u16 f2bf(float f) {
    u32 u = __float_as_uint(f);
    u32 r = (u + 0x7fffu + ((u >> 16) & 1u)) >> 16;  // RNE
    return (u16)r;
}
__device__ __forceinline__ float bf_lo(u32 u) { return __uint_as_float(u << 16); }
__device__ __forceinline__ float bf_hi(u32 u) { return __uint_as_float(u & 0xffff0000u); }

// ---------------- CSR build ----------------

__global__ void count_deg(const int* __restrict__ ei, int* __restrict__ deg) {
    int e = blockIdx.x * 256 + threadIdx.x;
    if (e < N_EDGES) atomicAdd(&deg[ei[N_EDGES + e]], 1);
}

__global__ __launch_bounds__(1024) void scan_blocks_k(const int* __restrict__ deg,
                                                      int* __restrict__ rs,
                                                      int* __restrict__ partials) {
    __shared__ int wsum[16];
    int i = blockIdx.x * 1024 + threadIdx.x;
    int v = (i < N_NODES) ? deg[i] : 0;
    int lane = threadIdx.x & 63, w = threadIdx.x >> 6;
    int s = v;
#pragma unroll
    for (int off = 1; off < 64; off <<= 1) {
        int t = __shfl_up(s, off, 64);
        if (lane >= off) s += t;
    }
    if (lane == 63) wsum[w] = s;
    __syncthreads();
    if (w == 0) {
        int ws = (lane < 16) ? wsum[lane] : 0;
#pragma unroll
        for (int off = 1; off < 16; off <<= 1) {
            int t = __shfl_up(ws, off, 64);
            if (lane >= off) ws += t;
        }
        if (lane < 16) wsum[lane] = ws;
    }
    __syncthreads();
    int incl = s + ((w > 0) ? wsum[w - 1] : 0);
    if (i < N_NODES) rs[i] = incl - v;  // exclusive
    if (threadIdx.x == 1023) partials[blockIdx.x] = incl;
}

__global__ void scan_partials_k(int* __restrict__ partials, int nb) {
    int tid = threadIdx.x;  // single wave, nb <= 64
    int v = (tid < nb) ? partials[tid] : 0;
    int orig = v;
    for (int off = 1; off < 64; off <<= 1) {
        int t = __shfl_up(v, off, 64);
        if (tid >= off) v += t;
    }
    if (tid < nb) partials[tid] = v - orig;
}

__global__ void finalize_csr(int* __restrict__ rs, const int* __restrict__ partials,
                             int* __restrict__ cursor, float* __restrict__ dinv,
                             const int* __restrict__ deg) {
    int i = blockIdx.x * 256 + threadIdx.x;
    if (i < N_NODES) {
        int r = rs[i] + partials[i >> 10];
        rs[i] = r;
        cursor[i] = r;
        dinv[i] = rsqrtf((float)(deg[i] + 1));
    }
    if (i == 0) rs[N_NODES] = N_EDGES;
}

__global__ void fill_csr(const int* __restrict__ ei, int* __restrict__ cursor,
                         int* __restrict__ col) {
    int e = blockIdx.x * 256 + threadIdx.x;
    if (e < N_EDGES) {
        int s = ei[e];
        int d = ei[N_EDGES + e];
        int pos = atomicAdd(&cursor[d], 1);
        col[pos] = s;
    }
}

// ---------------- weight prep: W[k][n] f32 -> Wt[n][k] bf16 ----------------

__global__ void prep_weights(const float* __restrict__ W1, const float* __restrict__ W2,
                             u16* __restrict__ W1t, u16* __restrict__ W2t) {
    int i = blockIdx.x * 256 + threadIdx.x;
    if (i < 128 * 128) {
        int n = i >> 7, k = i & 127;
        W1t[i] = f2bf(W1[k * 128 + n]);
    }
    if (i < 64 * 128) {
        int n = i >> 7, k = i & 127;
        W2t[i] = f2bf(W2[k * 64 + n]);
    }
}

// ---------------- GEMM1 (MFMA): hs1 = bf16((x @ W1) * dinv) ----------------
// M_BLK=64, N=128, K=128 one-shot. LDS row stride 136 u16 (272 B = 17x16B:
// 16B-aligned ds_read_b128, 2-way bank aliasing only).

#define SL 136

__global__ __launch_bounds__(256) void gemm1_mfma(const float* __restrict__ A,
                                                  const u16* __restrict__ Bt,
                                                  const float* __restrict__ dinv,
                                                  u16* __restrict__ out) {
    __shared__ u16 As[64 * SL];
    __shared__ u16 Bs[128 * SL];
    const int tid = threadIdx.x;
    const int m0 = blockIdx.x * 64;
    {   // stage A (fp32 -> bf16): thread t handles row t>>2, 32 floats
        int row = tid >> 2, c0 = (tid & 3) * 32;
        bool ok = (m0 + row) < N_NODES;
        const float4* src = (const float4*)&A[(size_t)(m0 + row) * 128 + c0];
        u16* dst = &As[row * SL + c0];
#pragma unroll
        for (int i = 0; i < 8; ++i) {  // 8 x float4 = 32 floats -> 32 u16
            float4 v = ok ? src[i] : make_float4(0.f, 0.f, 0.f, 0.f);
            u32 lo = (u32)f2bf(v.x) | ((u32)f2bf(v.y) << 16);
            u32 hi = (u32)f2bf(v.z) | ((u32)f2bf(v.w) << 16);
            *(uint2*)&dst[i * 4] = make_uint2(lo, hi);
        }
    }
    {   // stage B: W1t [128][128] bf16 -> Bs; thread t: row t>>1, 64 u16 = 8 uint4
        int n = tid >> 1, h = (tid & 1) * 64;
        const uint4* src = (const uint4*)&Bt[n * 128 + h];
        u16* dst = &Bs[n * SL + h];
#pragma unroll
        for (int i = 0; i < 8; ++i) *(uint4*)&dst[i * 8] = src[i];
    }
    __syncthreads();

    const int l = tid & 63, w = tid >> 6;
    const int q = l >> 4, r16 = l & 15;
    const int m_off = w * 16;
    f32x4 acc[8] = {};
#pragma unroll
    for (int kt = 0; kt < 128; kt += 32) {
        short8 a = *(const short8*)&As[(m_off + r16) * SL + kt + q * 8];
        short8 b[8];
#pragma unroll
        for (int tn = 0; tn < 8; ++tn)
            b[tn] = *(const short8*)&Bs[(tn * 16 + r16) * SL + kt + q * 8];
#pragma unroll
        for (int tn = 0; tn < 8; ++tn)
            acc[tn] = __builtin_amdgcn_mfma_f32_16x16x32_bf16(a, b[tn], acc[tn], 0, 0, 0);
    }
#pragma unroll
    for (int r = 0; r < 4; ++r) {
        int row = m0 + m_off + q * 4 + r;
        if (row < N_NODES) {
            float dv = dinv[row];
#pragma unroll
            for (int tn = 0; tn < 8; ++tn)
                out[(size_t)row * 128 + tn * 16 + r16] = f2bf(acc[tn][r] * dv);
        }
    }
}

// ---------------- GEMM2 (MFMA): hs2 = bf16((t1 @ W2) * dinv) ---------------
// M_BLK=128, N=64, K=128. A already bf16.

__global__ __launch_bounds__(256) void gemm2_mfma(const u16* __restrict__ A,
                                                  const u16* __restrict__ Bt,
                                                  const float* __restrict__ dinv,
                                                  u16* __restrict__ out) {
    __shared__ u16 As[128 * SL];
    __shared__ u16 Bs[64 * SL];
    const int tid = threadIdx.x;
    const int m0 = blockIdx.x * 128;
    {   // stage A: 128 rows x 128 bf16; thread t: row t>>1, 64 u16 = 8 uint4
        int row = tid >> 1, h = (tid & 1) * 64;
        bool ok = (m0 + row) < N_NODES;
        const uint4* src = (const uint4*)&A[(size_t)(m0 + row) * 128 + h];
        u16* dst = &As[row * SL + h];
#pragma unroll
        for (int i = 0; i < 8; ++i) {
            uint4 v = ok ? src[i] : make_uint4(0, 0, 0, 0);
            *(uint4*)&dst[i * 8] = v;
        }
    }
    {   // stage B: W2t [64][128] bf16; thread t: row t>>2, 32 u16 = 4 uint4
        int n = tid >> 2, s0 = (tid & 3) * 32;
        const uint4* src = (const uint4*)&Bt[n * 128 + s0];
        u16* dst = &Bs[n * SL + s0];
#pragma unroll
        for (int i = 0; i < 4; ++i) *(uint4*)&dst[i * 8] = src[i];
    }
    __syncthreads();

    const int l = tid & 63, w = tid >> 6;
    const int q = l >> 4, r16 = l & 15;
    const int m_base = w * 32;
    f32x4 acc[2][4] = {};
#pragma unroll
    for (int kt = 0; kt < 128; kt += 32) {
        short8 a[2];
        a[0] = *(const short8*)&As[(m_base + r16) * SL + kt + q * 8];
        a[1] = *(const short8*)&As[(m_base + 16 + r16) * SL + kt + q * 8];
        short8 b[4];
#pragma unroll
        for (int tn = 0; tn < 4; ++tn)
            b[tn] = *(const short8*)&Bs[(tn * 16 + r16) * SL + kt + q * 8];
#pragma unroll
        for (int tm = 0; tm < 2; ++tm)
#pragma unroll
            for (int tn = 0; tn < 4; ++tn)
                acc[tm][tn] =
                    __builtin_amdgcn_mfma_f32_16x16x32_bf16(a[tm], b[tn], acc[tm][tn], 0, 0, 0);
    }
#pragma unroll
    for (int tm = 0; tm < 2; ++tm)
#pragma unroll
        for (int r = 0; r < 4; ++r) {
            int row = m0 + m_base + tm * 16 + q * 4 + r;
            if (row < N_NODES) {
                float dv = dinv[row];
#pragma unroll
                for (int tn = 0; tn < 4; ++tn)
                    out[(size_t)row * 64 + tn * 16 + r16] = f2bf(acc[tm][tn][r] * dv);
            }
        }
}

// ---------------- Layer-1 aggregation (bf16 gather) + bias + ReLU -> bf16 --

__global__ __launch_bounds__(256) void agg_relu128_bf(const u16* __restrict__ hs,
                                                      const int* __restrict__ rs,
                                                      const int* __restrict__ col,
                                                      const float* __restrict__ dinv,
                                                      const float* __restrict__ bias,
                                                      u16* __restrict__ out) {
    int node = blockIdx.x * 16 + (threadIdx.x >> 4);
    int lane = threadIdx.x & 15;
    if (node >= N_NODES) return;
    const uint4* rows = (const uint4*)hs;  // 16 uint4 per row
    float acc[8] = {};
    auto accum = [&](uint4 v) {
        acc[0] += bf_lo(v.x); acc[1] += bf_hi(v.x);
        acc[2] += bf_lo(v.y); acc[3] += bf_hi(v.y);
        acc[4] += bf_lo(v.z); acc[5] += bf_hi(v.z);
        acc[6] += bf_lo(v.w); acc[7] += bf_hi(v.w);
    };
    accum(rows[(size_t)node * 16 + lane]);  // self-loop
    int e = rs[node], e1 = rs[node + 1];
    for (; e + 4 <= e1; e += 4) {
        int s0 = col[e], s1 = col[e + 1], s2 = col[e + 2], s3 = col[e + 3];
        uint4 v0 = rows[(size_t)s0 * 16 + lane];
        uint4 v1 = rows[(size_t)s1 * 16 + lane];
        uint4 v2 = rows[(size_t)s2 * 16 + lane];
        uint4 v3 = rows[(size_t)s3 * 16 + lane];
        accum(v0); accum(v1); accum(v2); accum(v3);
    }
    for (; e < e1; ++e) accum(rows[(size_t)col[e] * 16 + lane]);
    float dv = dinv[node];
    int fo = lane * 8;
    u32 pk[4];
#pragma unroll
    for (int j = 0; j < 4; ++j) {
        u16 a = f2bf(fmaxf(fmaf(dv, acc[2 * j], bias[fo + 2 * j]), 0.f));
        u16 b = f2bf(fmaxf(fmaf(dv, acc[2 * j + 1], bias[fo + 2 * j + 1]), 0.f));
        pk[j] = (u32)a | ((u32)b << 16);
    }
    *(uint4*)&out[(size_t)node * 128 + fo] = make_uint4(pk[0], pk[1], pk[2], pk[3]);
}

// ---------------- Layer-2 aggregation (bf16 gather) + ReLU + D->1 head -----

__global__ __launch_bounds__(256) void agg_final_bf(const u16* __restrict__ hs,
                                                    const int* __restrict__ rs,
                                                    const int* __restrict__ col,
                                                    const float* __restrict__ dinv,
                                                    const float* __restrict__ b2,
                                                    const float* __restrict__ W3,
                                                    const float* __restrict__ b3,
                                                    float* __restrict__ out) {
    int node = blockIdx.x * 32 + (threadIdx.x >> 3);
    int lane = threadIdx.x & 7;
    if (node >= N_NODES) return;
    const uint4* rows = (const uint4*)hs;  // 8 uint4 per row
    float acc[8] = {};
    auto accum = [&](uint4 v) {
        acc[0] += bf_lo(v.x); acc[1] += bf_hi(v.x);
        acc[2] += bf_lo(v.y); acc[3] += bf_hi(v.y);
        acc[4] += bf_lo(v.z); acc[5] += bf_hi(v.z);
        acc[6] += bf_lo(v.w); acc[7] += bf_hi(v.w);
    };
    accum(rows[(size_t)node * 8 + lane]);  // self-loop
    int e = rs[node], e1 = rs[node + 1];
    for (; e + 4 <= e1; e += 4) {
        int s0 = col[e], s1 = col[e + 1], s2 = col[e + 2], s3 = col[e + 3];
        uint4 v0 = rows[(size_t)s0 * 8 + lane];
        uint4 v1 = rows[(size_t)s1 * 8 + lane];
        uint4 v2 = rows[(size_t)s2 * 8 + lane];
        uint4 v3 = rows[(size_t)s3 * 8 + lane];
        accum(v0); accum(v1); accum(v2); accum(v3);
    }
    for (; e < e1; ++e) accum(rows[(size_t)col[e] * 8 + lane]);
    float dv = dinv[node];
    int fo = lane * 8;
    float v = 0.f;
#pragma unroll
    for (int j = 0; j < 8; ++j)
        v += fmaxf(fmaf(dv, acc[j], b2[fo + j]), 0.f) * W3[fo + j];
#pragma unroll
    for (int m = 4; m > 0; m >>= 1) v += __shfl_xor(v, m, 64);
    if (lane == 0) out[node] = v + b3[0];
}

// ---------------- launch ----------------

extern "C" void kernel_launch(void* const* d_in, const int* in_sizes, int n_in,
                              void* d_out, int out_size, void* d_ws, size_t ws_size,
                              hipStream_t stream) {
    const float* x  = (const float*)d_in[0];
    const int*   ei = (const int*)d_in[1];
    const float* W1 = (const float*)d_in[2];
    const float* b1 = (const float*)d_in[3];
    const float* W2 = (const float*)d_in[4];
    const float* b2 = (const float*)d_in[5];
    const float* W3 = (const float*)d_in[6];
    const float* b3 = (const float*)d_in[7];
    float* out = (float*)d_out;

    char* ws = (char*)d_ws;
    size_t off = 0;
    auto alloc = [&](size_t bytes) -> void* {
        void* p = ws + off;
        off = (off + bytes + 255) & ~(size_t)255;
        return p;
    };
    int*   deg      = (int*)alloc(N_NODES * sizeof(int));
    int*   rs       = (int*)alloc((N_NODES + 1) * sizeof(int));
    int*   cursor   = (int*)alloc(N_NODES * sizeof(int));
    int*   partials = (int*)alloc(64 * sizeof(int));
    int*   col      = (int*)alloc(N_EDGES * sizeof(int));
    float* dinv     = (float*)alloc(N_NODES * sizeof(float));
    u16*   W1t      = (u16*)alloc(128 * 128 * sizeof(u16));
    u16*   W2t      = (u16*)alloc(64 * 128 * sizeof(u16));
    u16*   hs1      = (u16*)alloc((size_t)N_NODES * 128 * sizeof(u16));
    u16*   t1       = (u16*)alloc((size_t)N_NODES * 128 * sizeof(u16));
    u16*   hs2      = (u16*)alloc((size_t)N_NODES * 64 * sizeof(u16));

    hipMemsetAsync(deg, 0, N_NODES * sizeof(int), stream);
    count_deg<<<(N_EDGES + 255) / 256, 256, 0, stream>>>(ei, deg);
    scan_blocks_k<<<SCAN_BLOCKS, 1024, 0, stream>>>(deg, rs, partials);
    scan_partials_k<<<1, 64, 0, stream>>>(partials, SCAN_BLOCKS);
    finalize_csr<<<(N_NODES + 255) / 256, 256, 0, stream>>>(rs, partials, cursor, dinv, deg);
    fill_csr<<<(N_EDGES + 255) / 256, 256, 0, stream>>>(ei, cursor, col);
    prep_weights<<<64, 256, 0, stream>>>(W1, W2, W1t, W2t);

    gemm1_mfma<<<(N_NODES + 63) / 64, 256, 0, stream>>>(x, W1t, dinv, hs1);
    agg_relu128_bf<<<(N_NODES + 15) / 16, 256, 0, stream>>>(hs1, rs, col, dinv, b1, t1);
    gemm2_mfma<<<(N_NODES + 127) / 128, 256, 0, stream>>>(t1, W2t, dinv, hs2);
    agg_final_bf<<<(N_NODES + 31) / 32, 256, 0, stream>>>(hs2, rs, col, dinv, b2, W3, b3, out);
}

// Round 6
// 188.680 us; speedup vs baseline: 1.9156x; 1.1182x over previous
//
#include <hip/hip_runtime.h>

#define N_NODES 50000
#define N_EDGES 600000
#define SCAN_BLOCKS ((N_NODES + 1023) / 1024)
#define CNT_BLOCKS ((N_EDGES + 255) / 256)

typedef unsigned int u32;
typedef unsigned short u16;
typedef __attribute__((ext_vector_type(8))) short short8;
typedef __attribute__((ext_vector_type(4))) float f32x4;

__device__ __forceinline__ u16 f2bf(float f) {
    u32 u = __float_as_uint(f);
    u32 r = (u + 0x7fffu + ((u >> 16) & 1u)) >> 16;  // RNE
    return (u16)r;
}
__device__ __forceinline__ float bf_lo(u32 u) { return __uint_as_float(u << 16); }
__device__ __forceinline__ float bf_hi(u32 u) { return __uint_as_float(u & 0xffff0000u); }

// ---------------- CSR build ----------------
// count_deg + weight transpose merged: blocks [0, CNT_BLOCKS) count edges and
// record each edge's rank within its dst bucket; blocks [CNT_BLOCKS, +96) do
// the W1/W2 fp32->bf16 transpose (24576 = 96*256 elements exactly).

__global__ void count_prep(const int* __restrict__ ei, int* __restrict__ deg,
                           int* __restrict__ rank,
                           const float* __restrict__ W1, const float* __restrict__ W2,
                           u16* __restrict__ W1t, u16* __restrict__ W2t) {
    int b = blockIdx.x;
    if (b < CNT_BLOCKS) {
        int e = b * 256 + threadIdx.x;
        if (e < N_EDGES) {
            int d = ei[N_EDGES + e];
            rank[e] = atomicAdd(&deg[d], 1);
        }
    } else {
        int i = (b - CNT_BLOCKS) * 256 + threadIdx.x;
        if (i < 128 * 128) {
            int n = i >> 7, k = i & 127;
            W1t[i] = f2bf(W1[k * 128 + n]);
        } else {
            int j = i - 128 * 128;  // j < 64*128
            int n = j >> 7, k = j & 127;
            W2t[j] = f2bf(W2[k * 64 + n]);
        }
    }
}

// block-level scan of deg -> rs (exclusive, local), partials; also dinv.
__global__ __launch_bounds__(1024) void scan_blocks_k(const int* __restrict__ deg,
                                                      int* __restrict__ rs,
                                                      int* __restrict__ partials,
                                                      float* __restrict__ dinv) {
    __shared__ int wsum[16];
    int i = blockIdx.x * 1024 + threadIdx.x;
    int v = (i < N_NODES) ? deg[i] : 0;
    if (i < N_NODES) dinv[i] = rsqrtf((float)(v + 1));  // +1 self-loop
    int lane = threadIdx.x & 63, w = threadIdx.x >> 6;
    int s = v;
#pragma unroll
    for (int off = 1; off < 64; off <<= 1) {
        int t = __shfl_up(s, off, 64);
        if (lane >= off) s += t;
    }
    if (lane == 63) wsum[w] = s;
    __syncthreads();
    if (w == 0) {
        int ws = (lane < 16) ? wsum[lane] : 0;
#pragma unroll
        for (int off = 1; off < 16; off <<= 1) {
            int t = __shfl_up(ws, off, 64);
            if (lane >= off) ws += t;
        }
        if (lane < 16) wsum[lane] = ws;
    }
    __syncthreads();
    int incl = s + ((w > 0) ? wsum[w - 1] : 0);
    if (i < N_NODES) rs[i] = incl - v;  // exclusive within block
    if (threadIdx.x == 1023) partials[blockIdx.x] = incl;
}

// finalize: each block re-scans the 49 partials in one wave (cheaper than a
// dependent dispatch), adds its group's prefix to rs.
__global__ __launch_bounds__(256) void finalize_csr(int* __restrict__ rs,
                                                    const int* __restrict__ partials) {
    __shared__ int spref;
    int b = blockIdx.x;
    if (threadIdx.x < 64) {
        int p = (threadIdx.x < SCAN_BLOCKS) ? partials[threadIdx.x] : 0;
        int orig = p;
#pragma unroll
        for (int off = 1; off < 64; off <<= 1) {
            int t = __shfl_up(p, off, 64);
            if ((threadIdx.x & 63) >= off) p += t;
        }
        if (threadIdx.x == (b >> 2)) spref = p - orig;  // exclusive prefix of group
    }
    __syncthreads();
    int i = b * 256 + threadIdx.x;
    if (i < N_NODES) rs[i] += spref;
    if (i == 0) rs[N_NODES] = N_EDGES;
}

// atomic-free fill using precomputed ranks.
__global__ void fill_csr(const int* __restrict__ ei, const int* __restrict__ rs,
                         const int* __restrict__ rank, int* __restrict__ col) {
    int e = blockIdx.x * 256 + threadIdx.x;
    if (e < N_EDGES) {
        int s = ei[e];
        int d = ei[N_EDGES + e];
        col[rs[d] + rank[e]] = s;
    }
}

// ---------------- GEMM1 (MFMA): hs1 = bf16((x @ W1) * dinv) ----------------
// M_BLK=64, N=128, K=128 one-shot. LDS row stride 136 u16 (272 B = 17x16B).

#define SL 136

__global__ __launch_bounds__(256) void gemm1_mfma(const float* __restrict__ A,
                                                  const u16* __restrict__ Bt,
                                                  const float* __restrict__ dinv,
                                                  u16* __restrict__ out) {
    __shared__ u16 As[64 * SL];
    __shared__ u16 Bs[128 * SL];
    const int tid = threadIdx.x;
    const int m0 = blockIdx.x * 64;
    {   // stage A (fp32 -> bf16): thread t handles row t>>2, 32 floats
        int row = tid >> 2, c0 = (tid & 3) * 32;
        bool ok = (m0 + row) < N_NODES;
        const float4* src = (const float4*)&A[(size_t)(m0 + row) * 128 + c0];
        u16* dst = &As[row * SL + c0];
#pragma unroll
        for (int i = 0; i < 8; ++i) {
            float4 v = ok ? src[i] : make_float4(0.f, 0.f, 0.f, 0.f);
            u32 lo = (u32)f2bf(v.x) | ((u32)f2bf(v.y) << 16);
            u32 hi = (u32)f2bf(v.z) | ((u32)f2bf(v.w) << 16);
            *(uint2*)&dst[i * 4] = make_uint2(lo, hi);
        }
    }
    {   // stage B: W1t [128][128] bf16; thread t: row t>>1, 64 u16 = 8 uint4
        int n = tid >> 1, h = (tid & 1) * 64;
        const uint4* src = (const uint4*)&Bt[n * 128 + h];
        u16* dst = &Bs[n * SL + h];
#pragma unroll
        for (int i = 0; i < 8; ++i) *(uint4*)&dst[i * 8] = src[i];
    }
    __syncthreads();

    const int l = tid & 63, w = tid >> 6;
    const int q = l >> 4, r16 = l & 15;
    const int m_off = w * 16;
    f32x4 acc[8] = {};
#pragma unroll
    for (int kt = 0; kt < 128; kt += 32) {
        short8 a = *(const short8*)&As[(m_off + r16) * SL + kt + q * 8];
        short8 b[8];
#pragma unroll
        for (int tn = 0; tn < 8; ++tn)
            b[tn] = *(const short8*)&Bs[(tn * 16 + r16) * SL + kt + q * 8];
#pragma unroll
        for (int tn = 0; tn < 8; ++tn)
            acc[tn] = __builtin_amdgcn_mfma_f32_16x16x32_bf16(a, b[tn], acc[tn], 0, 0, 0);
    }
#pragma unroll
    for (int r = 0; r < 4; ++r) {
        int row = m0 + m_off + q * 4 + r;
        if (row < N_NODES) {
            float dv = dinv[row];
#pragma unroll
            for (int tn = 0; tn < 8; ++tn)
                out[(size_t)row * 128 + tn * 16 + r16] = f2bf(acc[tn][r] * dv);
        }
    }
}

// ---------------- GEMM2 (MFMA): hs2 = bf16((t1 @ W2) * dinv) ---------------
// M_BLK=128, N=64, K=128. A already bf16.

__global__ __launch_bounds__(256) void gemm2_mfma(const u16* __restrict__ A,
                                                  const u16* __restrict__ Bt,
                                                  const float* __restrict__ dinv,
                                                  u16* __restrict__ out) {
    __shared__ u16 As[128 * SL];
    __shared__ u16 Bs[64 * SL];
    const int tid = threadIdx.x;
    const int m0 = blockIdx.x * 128;
    {   // stage A: thread t: row t>>1, 64 u16 = 8 uint4
        int row = tid >> 1, h = (tid & 1) * 64;
        bool ok = (m0 + row) < N_NODES;
        const uint4* src = (const uint4*)&A[(size_t)(m0 + row) * 128 + h];
        u16* dst = &As[row * SL + h];
#pragma unroll
        for (int i = 0; i < 8; ++i) {
            uint4 v = ok ? src[i] : make_uint4(0, 0, 0, 0);
            *(uint4*)&dst[i * 8] = v;
        }
    }
    {   // stage B: W2t [64][128]; thread t: row t>>2, 32 u16 = 4 uint4
        int n = tid >> 2, s0 = (tid & 3) * 32;
        const uint4* src = (const uint4*)&Bt[n * 128 + s0];
        u16* dst = &Bs[n * SL + s0];
#pragma unroll
        for (int i = 0; i < 4; ++i) *(uint4*)&dst[i * 8] = src[i];
    }
    __syncthreads();

    const int l = tid & 63, w = tid >> 6;
    const int q = l >> 4, r16 = l & 15;
    const int m_base = w * 32;
    f32x4 acc[2][4] = {};
#pragma unroll
    for (int kt = 0; kt < 128; kt += 32) {
        short8 a[2];
        a[0] = *(const short8*)&As[(m_base + r16) * SL + kt + q * 8];
        a[1] = *(const short8*)&As[(m_base + 16 + r16) * SL + kt + q * 8];
        short8 b[4];
#pragma unroll
        for (int tn = 0; tn < 4; ++tn)
            b[tn] = *(const short8*)&Bs[(tn * 16 + r16) * SL + kt + q * 8];
#pragma unroll
        for (int tm = 0; tm < 2; ++tm)
#pragma unroll
            for (int tn = 0; tn < 4; ++tn)
                acc[tm][tn] =
                    __builtin_amdgcn_mfma_f32_16x16x32_bf16(a[tm], b[tn], acc[tm][tn], 0, 0, 0);
    }
#pragma unroll
    for (int tm = 0; tm < 2; ++tm)
#pragma unroll
        for (int r = 0; r < 4; ++r) {
            int row = m0 + m_base + tm * 16 + q * 4 + r;
            if (row < N_NODES) {
                float dv = dinv[row];
#pragma unroll
                for (int tn = 0; tn < 4; ++tn)
                    out[(size_t)row * 64 + tn * 16 + r16] = f2bf(acc[tm][tn][r] * dv);
            }
        }
}

// ---------------- Layer-1 aggregation (bf16 gather, 8-deep) + ReLU -> bf16 -

__global__ __launch_bounds__(256) void agg_relu128_bf(const u16* __restrict__ hs,
                                                      const int* __restrict__ rs,
                                                      const int* __restrict__ col,
                                                      const float* __restrict__ dinv,
                                                      const float* __restrict__ bias,
                                                      u16* __restrict__ out) {
    int node = blockIdx.x * 16 + (threadIdx.x >> 4);
    int lane = threadIdx.x & 15;
    if (node >= N_NODES) return;
    const uint4* rows = (const uint4*)hs;  // 16 uint4 per row
    float acc[8] = {};
    auto accum = [&](uint4 v) {
        acc[0] += bf_lo(v.x); acc[1] += bf_hi(v.x);
        acc[2] += bf_lo(v.y); acc[3] += bf_hi(v.y);
        acc[4] += bf_lo(v.z); acc[5] += bf_hi(v.z);
        acc[6] += bf_lo(v.w); acc[7] += bf_hi(v.w);
    };
    accum(rows[(size_t)node * 16 + lane]);  // self-loop
    int e = rs[node], e1 = rs[node + 1];
    for (; e + 8 <= e1; e += 8) {
        int c[8];
#pragma unroll
        for (int j = 0; j < 8; ++j) c[j] = col[e + j];
        uint4 v[8];
#pragma unroll
        for (int j = 0; j < 8; ++j) v[j] = rows[(size_t)c[j] * 16 + lane];
#pragma unroll
        for (int j = 0; j < 8; ++j) accum(v[j]);
    }
    for (; e + 4 <= e1; e += 4) {
        int c[4];
#pragma unroll
        for (int j = 0; j < 4; ++j) c[j] = col[e + j];
        uint4 v[4];
#pragma unroll
        for (int j = 0; j < 4; ++j) v[j] = rows[(size_t)c[j] * 16 + lane];
#pragma unroll
        for (int j = 0; j < 4; ++j) accum(v[j]);
    }
    for (; e < e1; ++e) accum(rows[(size_t)col[e] * 16 + lane]);
    float dv = dinv[node];
    int fo = lane * 8;
    u32 pk[4];
#pragma unroll
    for (int j = 0; j < 4; ++j) {
        u16 a = f2bf(fmaxf(fmaf(dv, acc[2 * j], bias[fo + 2 * j]), 0.f));
        u16 b = f2bf(fmaxf(fmaf(dv, acc[2 * j + 1], bias[fo + 2 * j + 1]), 0.f));
        pk[j] = (u32)a | ((u32)b << 16);
    }
    *(uint4*)&out[(size_t)node * 128 + fo] = make_uint4(pk[0], pk[1], pk[2], pk[3]);
}

// ---------------- Layer-2 aggregation (8-deep) + ReLU + D->1 head ----------

__global__ __launch_bounds__(256) void agg_final_bf(const u16* __restrict__ hs,
                                                    const int* __restrict__ rs,
                                                    const int* __restrict__ col,
                                                    const float* __restrict__ dinv,
                                                    const float* __restrict__ b2,
                                                    const float* __restrict__ W3,
                                                    const float* __restrict__ b3,
                                                    float* __restrict__ out) {
    int node = blockIdx.x * 32 + (threadIdx.x >> 3);
    int lane = threadIdx.x & 7;
    if (node >= N_NODES) return;
    const uint4* rows = (const uint4*)hs;  // 8 uint4 per row
    float acc[8] = {};
    auto accum = [&](uint4 v) {
        acc[0] += bf_lo(v.x); acc[1] += bf_hi(v.x);
        acc[2] += bf_lo(v.y); acc[3] += bf_hi(v.y);
        acc[4] += bf_lo(v.z); acc[5] += bf_hi(v.z);
        acc[6] += bf_lo(v.w); acc[7] += bf_hi(v.w);
    };
    accum(rows[(size_t)node * 8 + lane]);  // self-loop
    int e = rs[node], e1 = rs[node + 1];
    for (; e + 8 <= e1; e += 8) {
        int c[8];
#pragma unroll
        for (int j = 0; j < 8; ++j) c[j] = col[e + j];
        uint4 v[8];
#pragma unroll
        for (int j = 0; j < 8; ++j) v[j] = rows[(size_t)c[j] * 8 + lane];
#pragma unroll
        for (int j = 0; j < 8; ++j) accum(v[j]);
    }
    for (; e + 4 <= e1; e += 4) {
        int c[4];
#pragma unroll
        for (int j = 0; j < 4; ++j) c[j] = col[e + j];
        uint4 v[4];
#pragma unroll
        for (int j = 0; j < 4; ++j) v[j] = rows[(size_t)c[j] * 8 + lane];
#pragma unroll
        for (int j = 0; j < 4; ++j) accum(v[j]);
    }
    for (; e < e1; ++e) accum(rows[(size_t)col[e] * 8 + lane]);
    float dv = dinv[node];
    int fo = lane * 8;
    float v = 0.f;
#pragma unroll
    for (int j = 0; j < 8; ++j)
        v += fmaxf(fmaf(dv, acc[j], b2[fo + j]), 0.f) * W3[fo + j];
#pragma unroll
    for (int m = 4; m > 0; m >>= 1) v += __shfl_xor(v, m, 64);
    if (lane == 0) out[node] = v + b3[0];
}

// ---------------- launch ----------------

extern "C" void kernel_launch(void* const* d_in, const int* in_sizes, int n_in,
                              void* d_out, int out_size, void* d_ws, size_t ws_size,
                              hipStream_t stream) {
    const float* x  = (const float*)d_in[0];
    const int*   ei = (const int*)d_in[1];
    const float* W1 = (const float*)d_in[2];
    const float* b1 = (const float*)d_in[3];
    const float* W2 = (const float*)d_in[4];
    const float* b2 = (const float*)d_in[5];
    const float* W3 = (const float*)d_in[6];
    const float* b3 = (const float*)d_in[7];
    float* out = (float*)d_out;

    char* ws = (char*)d_ws;
    size_t off = 0;
    auto alloc = [&](size_t bytes) -> void* {
        void* p = ws + off;
        off = (off + bytes + 255) & ~(size_t)255;
        return p;
    };
    int*   deg      = (int*)alloc(N_NODES * sizeof(int));
    int*   rs       = (int*)alloc((N_NODES + 1) * sizeof(int));
    int*   rank     = (int*)alloc(N_EDGES * sizeof(int));
    int*   partials = (int*)alloc(64 * sizeof(int));
    int*   col      = (int*)alloc(N_EDGES * sizeof(int));
    float* dinv     = (float*)alloc(N_NODES * sizeof(float));
    u16*   W1t      = (u16*)alloc(128 * 128 * sizeof(u16));
    u16*   W2t      = (u16*)alloc(64 * 128 * sizeof(u16));
    u16*   hs1      = (u16*)alloc((size_t)N_NODES * 128 * sizeof(u16));
    u16*   t1       = (u16*)alloc((size_t)N_NODES * 128 * sizeof(u16));
    u16*   hs2      = (u16*)alloc((size_t)N_NODES * 64 * sizeof(u16));

    hipMemsetAsync(deg, 0, N_NODES * sizeof(int), stream);
    count_prep<<<CNT_BLOCKS + 96, 256, 0, stream>>>(ei, deg, rank, W1, W2, W1t, W2t);
    scan_blocks_k<<<SCAN_BLOCKS, 1024, 0, stream>>>(deg, rs, partials, dinv);
    finalize_csr<<<(N_NODES + 255) / 256, 256, 0, stream>>>(rs, partials);
    fill_csr<<<(N_EDGES + 255) / 256, 256, 0, stream>>>(ei, rs, rank, col);

    gemm1_mfma<<<(N_NODES + 63) / 64, 256, 0, stream>>>(x, W1t, dinv, hs1);
    agg_relu128_bf<<<(N_NODES + 15) / 16, 256, 0, stream>>>(hs1, rs, col, dinv, b1, t1);
    gemm2_mfma<<<(N_NODES + 127) / 128, 256, 0, stream>>>(t1, W2t, dinv, hs2);
    agg_final_bf<<<(N_NODES + 31) / 32, 256, 0, stream>>>(hs2, rs, col, dinv, b2, W3, b3, out);
}

// Round 8
// 178.939 us; speedup vs baseline: 2.0198x; 1.0544x over previous
//
#include <hip/hip_runtime.h>

#define N_NODES 50000
#define N_EDGES 600000
#define SCAN_BLOCKS ((N_NODES + 1023) / 1024)
#define CNT_BLOCKS ((N_EDGES + 255) / 256)
#define GB1 ((N_NODES + 63) / 64)     // gemm1 blocks
#define FB  ((N_EDGES + 255) / 256)   // fill blocks

typedef unsigned int u32;
typedef unsigned short u16;
typedef __attribute__((ext_vector_type(8))) short short8;
typedef __attribute__((ext_vector_type(4))) float f32x4;

__device__ __forceinline__ u16 f2bf(float f) {
    u32 u = __float_as_uint(f);
    u32 r = (u + 0x7fffu + ((u >> 16) & 1u)) >> 16;  // RNE
    return (u16)r;
}
__device__ __forceinline__ float bf_lo(u32 u) { return __uint_as_float(u << 16); }
__device__ __forceinline__ float bf_hi(u32 u) { return __uint_as_float(u & 0xffff0000u); }

// one-wave exclusive scan of the 49 block partials into an LDS table.
// call from all threads; includes the trailing barrier.
__device__ __forceinline__ void load_pref(const int* __restrict__ partials, int* pref) {
    if (threadIdx.x < 64) {
        int t = threadIdx.x;
        int p = (t < SCAN_BLOCKS) ? partials[t] : 0;
        int orig = p;
#pragma unroll
        for (int off = 1; off < 64; off <<= 1) {
            int q = __shfl_up(p, off, 64);
            if (t >= off) p += q;
        }
        if (t < SCAN_BLOCKS) pref[t] = p - orig;
    }
    __syncthreads();
}

// ---------------- CSR build ----------------

__global__ void count_prep(const int* __restrict__ ei, int* __restrict__ deg,
                           int* __restrict__ rank,
                           const float* __restrict__ W1, const float* __restrict__ W2,
                           u16* __restrict__ W1t, u16* __restrict__ W2t) {
    int b = blockIdx.x;
    if (b < CNT_BLOCKS) {
        int e = b * 256 + threadIdx.x;
        if (e < N_EDGES) {
            int d = ei[N_EDGES + e];
            rank[e] = atomicAdd(&deg[d], 1);
        }
    } else {
        int i = (b - CNT_BLOCKS) * 256 + threadIdx.x;
        if (i < 128 * 128) {
            int n = i >> 7, k = i & 127;
            W1t[i] = f2bf(W1[k * 128 + n]);
        } else {
            int j = i - 128 * 128;  // j < 64*128
            int n = j >> 7, k = j & 127;
            W2t[j] = f2bf(W2[k * 64 + n]);
        }
    }
}

// block-local exclusive scan of deg -> rs, partials, dinv; rs[N]=local incl.
__global__ __launch_bounds__(1024) void scan_blocks_k(const int* __restrict__ deg,
                                                      int* __restrict__ rs,
                                                      int* __restrict__ partials,
                                                      float* __restrict__ dinv) {
    __shared__ int wsum[16];
    int i = blockIdx.x * 1024 + threadIdx.x;
    int v = (i < N_NODES) ? deg[i] : 0;
    if (i < N_NODES) dinv[i] = rsqrtf((float)(v + 1));  // +1 self-loop
    int lane = threadIdx.x & 63, w = threadIdx.x >> 6;
    int s = v;
#pragma unroll
    for (int off = 1; off < 64; off <<= 1) {
        int t = __shfl_up(s, off, 64);
        if (lane >= off) s += t;
    }
    if (lane == 63) wsum[w] = s;
    __syncthreads();
    if (w == 0) {
        int ws = (lane < 16) ? wsum[lane] : 0;
#pragma unroll
        for (int off = 1; off < 16; off <<= 1) {
            int t = __shfl_up(ws, off, 64);
            if (lane >= off) ws += t;
        }
        if (lane < 16) wsum[lane] = ws;
    }
    __syncthreads();
    int incl = s + ((w > 0) ? wsum[w - 1] : 0);
    if (i < N_NODES) rs[i] = incl - v;          // exclusive within block
    if (i == N_NODES - 1) rs[N_NODES] = incl;   // local incl; consumer adds pref
    if (threadIdx.x == 1023) partials[blockIdx.x] = incl;  // block total (R7 bug: was missing)
}

// ---------------- fused dispatch A: gemm1 (blocks [0,GB1)) + CSR fill ------

#define SL 136

__global__ __launch_bounds__(256) void gemm1_fill(const float* __restrict__ A,
                                                  const u16* __restrict__ Bt,
                                                  const float* __restrict__ dinv,
                                                  u16* __restrict__ out,
                                                  const int* __restrict__ ei,
                                                  const int* __restrict__ rs,
                                                  const int* __restrict__ rank,
                                                  const int* __restrict__ partials,
                                                  int* __restrict__ col) {
    __shared__ u16 As[64 * SL];
    __shared__ u16 Bs[128 * SL];
    __shared__ int pref[64];
    const int tid = threadIdx.x;
    const int b = blockIdx.x;
    if (b >= GB1) {  // ---- CSR fill branch (atomic-free) ----
        load_pref(partials, pref);
        int e = (b - GB1) * 256 + tid;
        if (e < N_EDGES) {
            int s = ei[e];
            int d = ei[N_EDGES + e];
            col[rs[d] + pref[d >> 10] + rank[e]] = s;
        }
        return;
    }
    // ---- gemm1 branch: hs1 = bf16((x @ W1) * dinv), M_BLK=64, N=128, K=128
    const int m0 = b * 64;
    {   // stage A (fp32 -> bf16): thread t handles row t>>2, 32 floats
        int row = tid >> 2, c0 = (tid & 3) * 32;
        bool ok = (m0 + row) < N_NODES;
        const float4* src = (const float4*)&A[(size_t)(m0 + row) * 128 + c0];
        u16* dst = &As[row * SL + c0];
#pragma unroll
        for (int i = 0; i < 8; ++i) {
            float4 v = ok ? src[i] : make_float4(0.f, 0.f, 0.f, 0.f);
            u32 lo = (u32)f2bf(v.x) | ((u32)f2bf(v.y) << 16);
            u32 hi = (u32)f2bf(v.z) | ((u32)f2bf(v.w) << 16);
            *(uint2*)&dst[i * 4] = make_uint2(lo, hi);
        }
    }
    {   // stage B: W1t [128][128]; thread t: row t>>1, 64 u16 = 8 uint4
        int n = tid >> 1, h = (tid & 1) * 64;
        const uint4* src = (const uint4*)&Bt[n * 128 + h];
        u16* dst = &Bs[n * SL + h];
#pragma unroll
        for (int i = 0; i < 8; ++i) *(uint4*)&dst[i * 8] = src[i];
    }
    __syncthreads();

    const int l = tid & 63, w = tid >> 6;
    const int q = l >> 4, r16 = l & 15;
    const int m_off = w * 16;
    f32x4 acc[8] = {};
#pragma unroll
    for (int kt = 0; kt < 128; kt += 32) {
        short8 a = *(const short8*)&As[(m_off + r16) * SL + kt + q * 8];
        short8 bb[8];
#pragma unroll
        for (int tn = 0; tn < 8; ++tn)
            bb[tn] = *(const short8*)&Bs[(tn * 16 + r16) * SL + kt + q * 8];
#pragma unroll
        for (int tn = 0; tn < 8; ++tn)
            acc[tn] = __builtin_amdgcn_mfma_f32_16x16x32_bf16(a, bb[tn], acc[tn], 0, 0, 0);
    }
#pragma unroll
    for (int r = 0; r < 4; ++r) {
        int row = m0 + m_off + q * 4 + r;
        if (row < N_NODES) {
            float dv = dinv[row];
#pragma unroll
            for (int tn = 0; tn < 8; ++tn)
                out[(size_t)row * 128 + tn * 16 + r16] = f2bf(acc[tn][r] * dv);
        }
    }
}

// ---------------- fused dispatch B: agg1(+bias+ReLU) -> LDS -> gemm2 -------
// Per 64-row tile: aggregate hs1 rows for the tile's nodes into As (bf16,
// identical f2bf(relu(...)) math as the old t1), then MFMA vs W2t.

__global__ __launch_bounds__(256) void agg_gemm2(const u16* __restrict__ hs,
                                                 const int* __restrict__ rs,
                                                 const int* __restrict__ partials,
                                                 const int* __restrict__ col,
                                                 const float* __restrict__ dinv,
                                                 const float* __restrict__ bias,
                                                 const u16* __restrict__ Bt,
                                                 u16* __restrict__ out) {
    __shared__ u16 As[64 * SL];
    __shared__ u16 Bs[64 * SL];
    __shared__ int pref[64];
    const int tid = threadIdx.x;
    const int m0 = blockIdx.x * 64;
    {   // stage B: W2t [64][128]; thread t: row t>>2, 32 u16 = 4 uint4
        int n = tid >> 2, s0 = (tid & 3) * 32;
        const uint4* src = (const uint4*)&Bt[n * 128 + s0];
        u16* dst = &Bs[n * SL + s0];
#pragma unroll
        for (int i = 0; i < 4; ++i) *(uint4*)&dst[i * 8] = src[i];
    }
    load_pref(partials, pref);

    // aggregation phase: 16 lanes/node, 16 nodes/pass, 4 passes.
    const uint4* rows = (const uint4*)hs;  // 16 uint4 per 128-feat row
    const int lane = tid & 15;
    const int fo = lane * 8;
#pragma unroll
    for (int p = 0; p < 4; ++p) {
        int nl = p * 16 + (tid >> 4);      // node_local in [0,64)
        int node = m0 + nl;
        uint4 pk = make_uint4(0, 0, 0, 0);
        if (node < N_NODES) {
            float acc[8] = {};
            auto accum = [&](uint4 v) {
                acc[0] += bf_lo(v.x); acc[1] += bf_hi(v.x);
                acc[2] += bf_lo(v.y); acc[3] += bf_hi(v.y);
                acc[4] += bf_lo(v.z); acc[5] += bf_hi(v.z);
                acc[6] += bf_lo(v.w); acc[7] += bf_hi(v.w);
            };
            accum(rows[(size_t)node * 16 + lane]);  // self-loop
            int e = rs[node] + pref[node >> 10];
            int e1 = rs[node + 1] + pref[(node + 1) >> 10];
            for (; e + 8 <= e1; e += 8) {
                int c[8];
#pragma unroll
                for (int j = 0; j < 8; ++j) c[j] = col[e + j];
                uint4 v[8];
#pragma unroll
                for (int j = 0; j < 8; ++j) v[j] = rows[(size_t)c[j] * 16 + lane];
#pragma unroll
                for (int j = 0; j < 8; ++j) accum(v[j]);
            }
            for (; e + 4 <= e1; e += 4) {
                int c[4];
#pragma unroll
                for (int j = 0; j < 4; ++j) c[j] = col[e + j];
                uint4 v[4];
#pragma unroll
                for (int j = 0; j < 4; ++j) v[j] = rows[(size_t)c[j] * 16 + lane];
#pragma unroll
                for (int j = 0; j < 4; ++j) accum(v[j]);
            }
            for (; e < e1; ++e) accum(rows[(size_t)col[e] * 16 + lane]);
            float dv = dinv[node];
            u32 w0[4];
#pragma unroll
            for (int j = 0; j < 4; ++j) {
                u16 a = f2bf(fmaxf(fmaf(dv, acc[2 * j], bias[fo + 2 * j]), 0.f));
                u16 b = f2bf(fmaxf(fmaf(dv, acc[2 * j + 1], bias[fo + 2 * j + 1]), 0.f));
                w0[j] = (u32)a | ((u32)b << 16);
            }
            pk = make_uint4(w0[0], w0[1], w0[2], w0[3]);
        }
        *(uint4*)&As[nl * SL + fo] = pk;
    }
    __syncthreads();

    // gemm2 phase: M=64, N=64, K=128
    const int l = tid & 63, w = tid >> 6;
    const int q = l >> 4, r16 = l & 15;
    const int m_off = w * 16;
    f32x4 acc[4] = {};
#pragma unroll
    for (int kt = 0; kt < 128; kt += 32) {
        short8 a = *(const short8*)&As[(m_off + r16) * SL + kt + q * 8];
        short8 bb[4];
#pragma unroll
        for (int tn = 0; tn < 4; ++tn)
            bb[tn] = *(const short8*)&Bs[(tn * 16 + r16) * SL + kt + q * 8];
#pragma unroll
        for (int tn = 0; tn < 4; ++tn)
            acc[tn] = __builtin_amdgcn_mfma_f32_16x16x32_bf16(a, bb[tn], acc[tn], 0, 0, 0);
    }
#pragma unroll
    for (int r = 0; r < 4; ++r) {
        int row = m0 + m_off + q * 4 + r;
        if (row < N_NODES) {
            float dv = dinv[row];
#pragma unroll
            for (int tn = 0; tn < 4; ++tn)
                out[(size_t)row * 64 + tn * 16 + r16] = f2bf(acc[tn][r] * dv);
        }
    }
}

// ---------------- Layer-2 aggregation (8-deep) + ReLU + D->1 head ----------

__global__ __launch_bounds__(256) void agg_final_bf(const u16* __restrict__ hs,
                                                    const int* __restrict__ rs,
                                                    const int* __restrict__ partials,
                                                    const int* __restrict__ col,
                                                    const float* __restrict__ dinv,
                                                    const float* __restrict__ b2,
                                                    const float* __restrict__ W3,
                                                    const float* __restrict__ b3,
                                                    float* __restrict__ out) {
    __shared__ int pref[64];
    load_pref(partials, pref);
    int node = blockIdx.x * 32 + (threadIdx.x >> 3);
    int lane = threadIdx.x & 7;
    if (node >= N_NODES) return;
    const uint4* rows = (const uint4*)hs;  // 8 uint4 per 64-feat row
    float acc[8] = {};
    auto accum = [&](uint4 v) {
        acc[0] += bf_lo(v.x); acc[1] += bf_hi(v.x);
        acc[2] += bf_lo(v.y); acc[3] += bf_hi(v.y);
        acc[4] += bf_lo(v.z); acc[5] += bf_hi(v.z);
        acc[6] += bf_lo(v.w); acc[7] += bf_hi(v.w);
    };
    accum(rows[(size_t)node * 8 + lane]);  // self-loop
    int e = rs[node] + pref[node >> 10];
    int e1 = rs[node + 1] + pref[(node + 1) >> 10];
    for (; e + 8 <= e1; e += 8) {
        int c[8];
#pragma unroll
        for (int j = 0; j < 8; ++j) c[j] = col[e + j];
        uint4 v[8];
#pragma unroll
        for (int j = 0; j < 8; ++j) v[j] = rows[(size_t)c[j] * 8 + lane];
#pragma unroll
        for (int j = 0; j < 8; ++j) accum(v[j]);
    }
    for (; e + 4 <= e1; e += 4) {
        int c[4];
#pragma unroll
        for (int j = 0; j < 4; ++j) c[j] = col[e + j];
        uint4 v[4];
#pragma unroll
        for (int j = 0; j < 4; ++j) v[j] = rows[(size_t)c[j] * 8 + lane];
#pragma unroll
        for (int j = 0; j < 4; ++j) accum(v[j]);
    }
    for (; e < e1; ++e) accum(rows[(size_t)col[e] * 8 + lane]);
    float dv = dinv[node];
    int fo = lane * 8;
    float v = 0.f;
#pragma unroll
    for (int j = 0; j < 8; ++j)
        v += fmaxf(fmaf(dv, acc[j], b2[fo + j]), 0.f) * W3[fo + j];
#pragma unroll
    for (int m = 4; m > 0; m >>= 1) v += __shfl_xor(v, m, 64);
    if (lane == 0) out[node] = v + b3[0];
}

// ---------------- launch ----------------

extern "C" void kernel_launch(void* const* d_in, const int* in_sizes, int n_in,
                              void* d_out, int out_size, void* d_ws, size_t ws_size,
                              hipStream_t stream) {
    const float* x  = (const float*)d_in[0];
    const int*   ei = (const int*)d_in[1];
    const float* W1 = (const float*)d_in[2];
    const float* b1 = (const float*)d_in[3];
    const float* W2 = (const float*)d_in[4];
    const float* b2 = (const float*)d_in[5];
    const float* W3 = (const float*)d_in[6];
    const float* b3 = (const float*)d_in[7];
    float* out = (float*)d_out;

    char* ws = (char*)d_ws;
    size_t off = 0;
    auto alloc = [&](size_t bytes) -> void* {
        void* p = ws + off;
        off = (off + bytes + 255) & ~(size_t)255;
        return p;
    };
    int*   deg      = (int*)alloc(N_NODES * sizeof(int));
    int*   rs       = (int*)alloc((N_NODES + 1) * sizeof(int));
    int*   rank     = (int*)alloc(N_EDGES * sizeof(int));
    int*   partials = (int*)alloc(64 * sizeof(int));
    int*   col      = (int*)alloc(N_EDGES * sizeof(int));
    float* dinv     = (float*)alloc(N_NODES * sizeof(float));
    u16*   W1t      = (u16*)alloc(128 * 128 * sizeof(u16));
    u16*   W2t      = (u16*)alloc(64 * 128 * sizeof(u16));
    u16*   hs1      = (u16*)alloc((size_t)N_NODES * 128 * sizeof(u16));
    u16*   hs2      = (u16*)alloc((size_t)N_NODES * 64 * sizeof(u16));

    hipMemsetAsync(deg, 0, N_NODES * sizeof(int), stream);
    count_prep<<<CNT_BLOCKS + 96, 256, 0, stream>>>(ei, deg, rank, W1, W2, W1t, W2t);
    scan_blocks_k<<<SCAN_BLOCKS, 1024, 0, stream>>>(deg, rs, partials, dinv);
    gemm1_fill<<<GB1 + FB, 256, 0, stream>>>(x, W1t, dinv, hs1, ei, rs, rank, partials, col);
    agg_gemm2<<<(N_NODES + 63) / 64, 256, 0, stream>>>(hs1, rs, partials, col, dinv, b1,
                                                       W2t, hs2);
    agg_final_bf<<<(N_NODES + 31) / 32, 256, 0, stream>>>(hs2, rs, partials, col, dinv,
                                                          b2, W3, b3, out);
}

// Round 9
// 178.817 us; speedup vs baseline: 2.0212x; 1.0007x over previous
//
#include <hip/hip_runtime.h>

#define N_NODES 50000
#define N_EDGES 600000
#define SCAN_BLOCKS ((N_NODES + 1023) / 1024)
#define CNT_BLOCKS ((N_EDGES + 255) / 256)
#define GB1 ((N_NODES + 63) / 64)     // gemm1 blocks
#define FB  ((N_EDGES + 255) / 256)   // fill blocks

typedef unsigned int u32;
typedef unsigned short u16;
typedef __attribute__((ext_vector_type(8))) short short8;
typedef __attribute__((ext_vector_type(4))) float f32x4;

__device__ __forceinline__ u16 f2bf(float f) {
    u32 u = __float_as_uint(f);
    u32 r = (u + 0x7fffu + ((u >> 16) & 1u)) >> 16;  // RNE
    return (u16)r;
}
__device__ __forceinline__ float bf_lo(u32 u) { return __uint_as_float(u << 16); }
__device__ __forceinline__ float bf_hi(u32 u) { return __uint_as_float(u & 0xffff0000u); }

// one-wave exclusive scan of the 49 block partials into an LDS table.
__device__ __forceinline__ void load_pref(const int* __restrict__ partials, int* pref) {
    if (threadIdx.x < 64) {
        int t = threadIdx.x;
        int p = (t < SCAN_BLOCKS) ? partials[t] : 0;
        int orig = p;
#pragma unroll
        for (int off = 1; off < 64; off <<= 1) {
            int q = __shfl_up(p, off, 64);
            if (t >= off) p += q;
        }
        if (t < SCAN_BLOCKS) pref[t] = p - orig;
    }
    __syncthreads();
}

// ---------------- CSR build ----------------

__global__ void count_prep(const int* __restrict__ ei, int* __restrict__ deg,
                           int* __restrict__ rank,
                           const float* __restrict__ W1, const float* __restrict__ W2,
                           u16* __restrict__ W1t, u16* __restrict__ W2t) {
    int b = blockIdx.x;
    if (b < CNT_BLOCKS) {
        int e = b * 256 + threadIdx.x;
        if (e < N_EDGES) {
            int d = ei[N_EDGES + e];
            rank[e] = atomicAdd(&deg[d], 1);
        }
    } else {
        int i = (b - CNT_BLOCKS) * 256 + threadIdx.x;
        if (i < 128 * 128) {
            int n = i >> 7, k = i & 127;
            W1t[i] = f2bf(W1[k * 128 + n]);
        } else {
            int j = i - 128 * 128;  // j < 64*128
            int n = j >> 7, k = j & 127;
            W2t[j] = f2bf(W2[k * 64 + n]);
        }
    }
}

// block-local exclusive scan of deg -> rs, partials, dinv; rs[N]=local incl.
__global__ __launch_bounds__(1024) void scan_blocks_k(const int* __restrict__ deg,
                                                      int* __restrict__ rs,
                                                      int* __restrict__ partials,
                                                      float* __restrict__ dinv) {
    __shared__ int wsum[16];
    int i = blockIdx.x * 1024 + threadIdx.x;
    int v = (i < N_NODES) ? deg[i] : 0;
    if (i < N_NODES) dinv[i] = rsqrtf((float)(v + 1));  // +1 self-loop
    int lane = threadIdx.x & 63, w = threadIdx.x >> 6;
    int s = v;
#pragma unroll
    for (int off = 1; off < 64; off <<= 1) {
        int t = __shfl_up(s, off, 64);
        if (lane >= off) s += t;
    }
    if (lane == 63) wsum[w] = s;
    __syncthreads();
    if (w == 0) {
        int ws = (lane < 16) ? wsum[lane] : 0;
#pragma unroll
        for (int off = 1; off < 16; off <<= 1) {
            int t = __shfl_up(ws, off, 64);
            if (lane >= off) ws += t;
        }
        if (lane < 16) wsum[lane] = ws;
    }
    __syncthreads();
    int incl = s + ((w > 0) ? wsum[w - 1] : 0);
    if (i < N_NODES) rs[i] = incl - v;          // exclusive within block
    if (i == N_NODES - 1) rs[N_NODES] = incl;   // local incl; consumer adds pref
    if (threadIdx.x == 1023) partials[blockIdx.x] = incl;  // block total
}

// ---------------- fused dispatch A: gemm1 (blocks [0,GB1)) + CSR fill ------

#define SL 136

__global__ __launch_bounds__(256) void gemm1_fill(const float* __restrict__ A,
                                                  const u16* __restrict__ Bt,
                                                  const float* __restrict__ dinv,
                                                  u16* __restrict__ out,
                                                  const int* __restrict__ ei,
                                                  const int* __restrict__ rs,
                                                  const int* __restrict__ rank,
                                                  const int* __restrict__ partials,
                                                  int* __restrict__ col) {
    __shared__ u16 As[64 * SL];
    __shared__ u16 Bs[128 * SL];
    __shared__ int pref[64];
    const int tid = threadIdx.x;
    const int b = blockIdx.x;
    if (b >= GB1) {  // ---- CSR fill branch (atomic-free) ----
        load_pref(partials, pref);
        int e = (b - GB1) * 256 + tid;
        if (e < N_EDGES) {
            int s = ei[e];
            int d = ei[N_EDGES + e];
            col[rs[d] + pref[d >> 10] + rank[e]] = s;
        }
        return;
    }
    // ---- gemm1 branch: hs1 = bf16((x @ W1) * dinv), M_BLK=64, N=128, K=128
    const int m0 = b * 64;
    {   // stage A (fp32 -> bf16): thread t handles row t>>2, 32 floats
        int row = tid >> 2, c0 = (tid & 3) * 32;
        bool ok = (m0 + row) < N_NODES;
        const float4* src = (const float4*)&A[(size_t)(m0 + row) * 128 + c0];
        u16* dst = &As[row * SL + c0];
#pragma unroll
        for (int i = 0; i < 8; ++i) {
            float4 v = ok ? src[i] : make_float4(0.f, 0.f, 0.f, 0.f);
            u32 lo = (u32)f2bf(v.x) | ((u32)f2bf(v.y) << 16);
            u32 hi = (u32)f2bf(v.z) | ((u32)f2bf(v.w) << 16);
            *(uint2*)&dst[i * 4] = make_uint2(lo, hi);
        }
    }
    {   // stage B: W1t [128][128]; thread t: row t>>1, 64 u16 = 8 uint4
        int n = tid >> 1, h = (tid & 1) * 64;
        const uint4* src = (const uint4*)&Bt[n * 128 + h];
        u16* dst = &Bs[n * SL + h];
#pragma unroll
        for (int i = 0; i < 8; ++i) *(uint4*)&dst[i * 8] = src[i];
    }
    __syncthreads();

    const int l = tid & 63, w = tid >> 6;
    const int q = l >> 4, r16 = l & 15;
    const int m_off = w * 16;
    f32x4 acc[8] = {};
#pragma unroll
    for (int kt = 0; kt < 128; kt += 32) {
        short8 a = *(const short8*)&As[(m_off + r16) * SL + kt + q * 8];
        short8 bb[8];
#pragma unroll
        for (int tn = 0; tn < 8; ++tn)
            bb[tn] = *(const short8*)&Bs[(tn * 16 + r16) * SL + kt + q * 8];
#pragma unroll
        for (int tn = 0; tn < 8; ++tn)
            acc[tn] = __builtin_amdgcn_mfma_f32_16x16x32_bf16(a, bb[tn], acc[tn], 0, 0, 0);
    }
#pragma unroll
    for (int r = 0; r < 4; ++r) {
        int row = m0 + m_off + q * 4 + r;
        if (row < N_NODES) {
            float dv = dinv[row];
#pragma unroll
            for (int tn = 0; tn < 8; ++tn)
                out[(size_t)row * 128 + tn * 16 + r16] = f2bf(acc[tn][r] * dv);
        }
    }
}

// ---------------- fused dispatch B: agg1(+bias+ReLU) -> LDS -> gemm2 -------
// Gather loop: single predicated 8-wide round structure — exactly
// ceil(deg/8) dependent latency rounds per node, no scalar tail.

__global__ __launch_bounds__(256) void agg_gemm2(const u16* __restrict__ hs,
                                                 const int* __restrict__ rs,
                                                 const int* __restrict__ partials,
                                                 const int* __restrict__ col,
                                                 const float* __restrict__ dinv,
                                                 const float* __restrict__ bias,
                                                 const u16* __restrict__ Bt,
                                                 u16* __restrict__ out) {
    __shared__ u16 As[64 * SL];
    __shared__ u16 Bs[64 * SL];
    __shared__ int pref[64];
    const int tid = threadIdx.x;
    const int m0 = blockIdx.x * 64;
    {   // stage B: W2t [64][128]; thread t: row t>>2, 32 u16 = 4 uint4
        int n = tid >> 2, s0 = (tid & 3) * 32;
        const uint4* src = (const uint4*)&Bt[n * 128 + s0];
        u16* dst = &Bs[n * SL + s0];
#pragma unroll
        for (int i = 0; i < 4; ++i) *(uint4*)&dst[i * 8] = src[i];
    }
    load_pref(partials, pref);

    // aggregation phase: 16 lanes/node, 16 nodes/pass, 4 passes.
    const uint4* rows = (const uint4*)hs;  // 16 uint4 per 128-feat row
    const int lane = tid & 15;
    const int fo = lane * 8;
#pragma unroll
    for (int p = 0; p < 4; ++p) {
        int nl = p * 16 + (tid >> 4);      // node_local in [0,64)
        int node = m0 + nl;
        uint4 pk = make_uint4(0, 0, 0, 0);
        if (node < N_NODES) {
            float acc[8] = {};
            auto accum = [&](uint4 v) {
                acc[0] += bf_lo(v.x); acc[1] += bf_hi(v.x);
                acc[2] += bf_lo(v.y); acc[3] += bf_hi(v.y);
                acc[4] += bf_lo(v.z); acc[5] += bf_hi(v.z);
                acc[6] += bf_lo(v.w); acc[7] += bf_hi(v.w);
            };
            accum(rows[(size_t)node * 16 + lane]);  // self-loop
            int e = rs[node] + pref[node >> 10];
            int e1 = rs[node + 1] + pref[(node + 1) >> 10];
            for (; e < e1; e += 8) {
                int c[8];
#pragma unroll
                for (int j = 0; j < 8; ++j) {
                    int idx = e + j;
                    c[j] = col[idx < e1 ? idx : e1 - 1];  // clamp: dup loads hit L1
                }
                uint4 v[8];
#pragma unroll
                for (int j = 0; j < 8; ++j) v[j] = rows[(size_t)c[j] * 16 + lane];
#pragma unroll
                for (int j = 0; j < 8; ++j) {
                    uint4 vv = (e + j < e1) ? v[j] : make_uint4(0, 0, 0, 0);
                    accum(vv);
                }
            }
            float dv = dinv[node];
            u32 w0[4];
#pragma unroll
            for (int j = 0; j < 4; ++j) {
                u16 a = f2bf(fmaxf(fmaf(dv, acc[2 * j], bias[fo + 2 * j]), 0.f));
                u16 b = f2bf(fmaxf(fmaf(dv, acc[2 * j + 1], bias[fo + 2 * j + 1]), 0.f));
                w0[j] = (u32)a | ((u32)b << 16);
            }
            pk = make_uint4(w0[0], w0[1], w0[2], w0[3]);
        }
        *(uint4*)&As[nl * SL + fo] = pk;
    }
    __syncthreads();

    // gemm2 phase: M=64, N=64, K=128
    const int l = tid & 63, w = tid >> 6;
    const int q = l >> 4, r16 = l & 15;
    const int m_off = w * 16;
    f32x4 acc[4] = {};
#pragma unroll
    for (int kt = 0; kt < 128; kt += 32) {
        short8 a = *(const short8*)&As[(m_off + r16) * SL + kt + q * 8];
        short8 bb[4];
#pragma unroll
        for (int tn = 0; tn < 4; ++tn)
            bb[tn] = *(const short8*)&Bs[(tn * 16 + r16) * SL + kt + q * 8];
#pragma unroll
        for (int tn = 0; tn < 4; ++tn)
            acc[tn] = __builtin_amdgcn_mfma_f32_16x16x32_bf16(a, bb[tn], acc[tn], 0, 0, 0);
    }
#pragma unroll
    for (int r = 0; r < 4; ++r) {
        int row = m0 + m_off + q * 4 + r;
        if (row < N_NODES) {
            float dv = dinv[row];
#pragma unroll
            for (int tn = 0; tn < 4; ++tn)
                out[(size_t)row * 64 + tn * 16 + r16] = f2bf(acc[tn][r] * dv);
        }
    }
}

// ---------------- Layer-2 aggregation (predicated 8-wide) + head -----------

__global__ __launch_bounds__(256) void agg_final_bf(const u16* __restrict__ hs,
                                                    const int* __restrict__ rs,
                                                    const int* __restrict__ partials,
                                                    const int* __restrict__ col,
                                                    const float* __restrict__ dinv,
                                                    const float* __restrict__ b2,
                                                    const float* __restrict__ W3,
                                                    const float* __restrict__ b3,
                                                    float* __restrict__ out) {
    __shared__ int pref[64];
    load_pref(partials, pref);
    int node = blockIdx.x * 32 + (threadIdx.x >> 3);
    int lane = threadIdx.x & 7;
    if (node >= N_NODES) return;
    const uint4* rows = (const uint4*)hs;  // 8 uint4 per 64-feat row
    float acc[8] = {};
    auto accum = [&](uint4 v) {
        acc[0] += bf_lo(v.x); acc[1] += bf_hi(v.x);
        acc[2] += bf_lo(v.y); acc[3] += bf_hi(v.y);
        acc[4] += bf_lo(v.z); acc[5] += bf_hi(v.z);
        acc[6] += bf_lo(v.w); acc[7] += bf_hi(v.w);
    };
    accum(rows[(size_t)node * 8 + lane]);  // self-loop
    int e = rs[node] + pref[node >> 10];
    int e1 = rs[node + 1] + pref[(node + 1) >> 10];
    for (; e < e1; e += 8) {
        int c[8];
#pragma unroll
        for (int j = 0; j < 8; ++j) {
            int idx = e + j;
            c[j] = col[idx < e1 ? idx : e1 - 1];
        }
        uint4 v[8];
#pragma unroll
        for (int j = 0; j < 8; ++j) v[j] = rows[(size_t)c[j] * 8 + lane];
#pragma unroll
        for (int j = 0; j < 8; ++j) {
            uint4 vv = (e + j < e1) ? v[j] : make_uint4(0, 0, 0, 0);
            accum(vv);
        }
    }
    float dv = dinv[node];
    int fo = lane * 8;
    float v = 0.f;
#pragma unroll
    for (int j = 0; j < 8; ++j)
        v += fmaxf(fmaf(dv, acc[j], b2[fo + j]), 0.f) * W3[fo + j];
#pragma unroll
    for (int m = 4; m > 0; m >>= 1) v += __shfl_xor(v, m, 64);
    if (lane == 0) out[node] = v + b3[0];
}

// ---------------- launch ----------------

extern "C" void kernel_launch(void* const* d_in, const int* in_sizes, int n_in,
                              void* d_out, int out_size, void* d_ws, size_t ws_size,
                              hipStream_t stream) {
    const float* x  = (const float*)d_in[0];
    const int*   ei = (const int*)d_in[1];
    const float* W1 = (const float*)d_in[2];
    const float* b1 = (const float*)d_in[3];
    const float* W2 = (const float*)d_in[4];
    const float* b2 = (const float*)d_in[5];
    const float* W3 = (const float*)d_in[6];
    const float* b3 = (const float*)d_in[7];
    float* out = (float*)d_out;

    char* ws = (char*)d_ws;
    size_t off = 0;
    auto alloc = [&](size_t bytes) -> void* {
        void* p = ws + off;
        off = (off + bytes + 255) & ~(size_t)255;
        return p;
    };
    int*   deg      = (int*)alloc(N_NODES * sizeof(int));
    int*   rs       = (int*)alloc((N_NODES + 1) * sizeof(int));
    int*   rank     = (int*)alloc(N_EDGES * sizeof(int));
    int*   partials = (int*)alloc(64 * sizeof(int));
    int*   col      = (int*)alloc(N_EDGES * sizeof(int));
    float* dinv     = (float*)alloc(N_NODES * sizeof(float));
    u16*   W1t      = (u16*)alloc(128 * 128 * sizeof(u16));
    u16*   W2t      = (u16*)alloc(64 * 128 * sizeof(u16));
    u16*   hs1      = (u16*)alloc((size_t)N_NODES * 128 * sizeof(u16));
    u16*   hs2      = (u16*)alloc((size_t)N_NODES * 64 * sizeof(u16));

    hipMemsetAsync(deg, 0, N_NODES * sizeof(int), stream);
    count_prep<<<CNT_BLOCKS + 96, 256, 0, stream>>>(ei, deg, rank, W1, W2, W1t, W2t);
    scan_blocks_k<<<SCAN_BLOCKS, 1024, 0, stream>>>(deg, rs, partials, dinv);
    gemm1_fill<<<GB1 + FB, 256, 0, stream>>>(x, W1t, dinv, hs1, ei, rs, rank, partials, col);
    agg_gemm2<<<(N_NODES + 63) / 64, 256, 0, stream>>>(hs1, rs, partials, col, dinv, b1,
                                                       W2t, hs2);
    agg_final_bf<<<(N_NODES + 31) / 32, 256, 0, stream>>>(hs2, rs, partials, col, dinv,
                                                          b2, W3, b3, out);
}